// Round 7
// baseline (906.081 us; speedup 1.0000x reference)
//
#include <hip/hip_runtime.h>

#define BQ 4
#define CQ 512
#define TQ 1024
#define FQ 2048
#define LQ 4
#define HQ 8
#define MT (BQ * TQ)            // batch-folded rows = 4096

typedef __attribute__((ext_vector_type(8))) short short8;
typedef __attribute__((ext_vector_type(4))) float floatx4;

#define MFMA16(a, b, c) __builtin_amdgcn_mfma_f32_16x16x32_bf16(a, b, c, 0, 0, 0)

static __device__ __forceinline__ unsigned short f2bf(float f) {
  union { float f; unsigned u; } v; v.f = f;
  unsigned r = v.u + 0x7fff + ((v.u >> 16) & 1);
  return (unsigned short)(r >> 16);
}

static __device__ __forceinline__ void async_copy16(const void* g, void* l) {
  __builtin_amdgcn_global_load_lds(
      (const __attribute__((address_space(1))) void*)g,
      (__attribute__((address_space(3))) void*)l, 16, 0, 0);
}

// ---------------------------------------------------------------------------
// bf16 MFMA GEMM: Y[m,n] = epi( sum_k A[m, ko+k] B[n, ko+k] ), ko = z*kofs
// 128x128 tile, BK=32, 4 waves (2x2). flags: 1=relu 2=premask(row m)
// 4=postmask(row m) 16=bf16 out 32=raw fp32 (split-K partial, Y += z*sYb)
// ---------------------------------------------------------------------------
__global__ __launch_bounds__(256) void mfma_gemm(
    const unsigned short* __restrict__ A, const unsigned short* __restrict__ B,
    void* __restrict__ Y, const float* __restrict__ bias,
    const float* __restrict__ mask, int M, int N, int K, int lda, int ldb,
    long long kofs, long long sYb, float scale, int flags)
{
  const int tid = threadIdx.x;
  const int w = tid >> 6, lane = tid & 63;
  const int wm = w >> 1, wn = w & 1;
  const int m0 = blockIdx.y * 128, n0 = blockIdx.x * 128;
  const size_t ko = (size_t)blockIdx.z * kofs;

  __shared__ unsigned short sA[128 * 32];
  __shared__ unsigned short sB[128 * 32];

  floatx4 acc[4][4];
#pragma unroll
  for (int i = 0; i < 4; i++)
#pragma unroll
    for (int j = 0; j < 4; j++) acc[i][j] = floatx4{0.f, 0.f, 0.f, 0.f};

  const int srow = lane >> 2;
  const int skel = (lane & 3) * 8;
  const int col = lane & 15, gq = lane >> 4;

  for (int k0 = 0; k0 < K; k0 += 32) {
#pragma unroll
    for (int r = 0; r < 2; r++) {
      int c = r * 4 + w;
      async_copy16(&A[(size_t)(m0 + c * 16 + srow) * lda + ko + k0 + skel],
                   &sA[c * 512]);
      async_copy16(&B[(size_t)(n0 + c * 16 + srow) * ldb + ko + k0 + skel],
                   &sB[c * 512]);
    }
    __syncthreads();

    short8 af[4], bfr[4];
#pragma unroll
    for (int im = 0; im < 4; im++)
      af[im] = *(const short8*)&sA[(wm * 64 + im * 16 + col) * 32 + gq * 8];
#pragma unroll
    for (int in = 0; in < 4; in++)
      bfr[in] = *(const short8*)&sB[(wn * 64 + in * 16 + col) * 32 + gq * 8];
#pragma unroll
    for (int im = 0; im < 4; im++)
#pragma unroll
      for (int in = 0; in < 4; in++)
        acc[im][in] = MFMA16(af[im], bfr[in], acc[im][in]);
    __syncthreads();
  }

  const bool relu  = flags & 1;
  const bool prem  = flags & 2;
  const bool postm = flags & 4;
  const bool bf16o = flags & 16;
  const bool raw   = flags & 32;
  float* Yf = (float*)Y + (size_t)blockIdx.z * sYb;
  unsigned short* Yh = (unsigned short*)Y;

#pragma unroll
  for (int im = 0; im < 4; im++)
#pragma unroll
    for (int in = 0; in < 4; in++) {
      int nn = n0 + wn * 64 + in * 16 + col;
      float bn = raw ? 0.f : bias[nn];
#pragma unroll
      for (int reg = 0; reg < 4; reg++) {
        int mm = m0 + wm * 64 + im * 16 + gq * 4 + reg;
        float val = acc[im][in][reg];
        if (raw) {
          Yf[(size_t)mm * N + nn] = val;
        } else {
          float mv = (prem || postm) ? mask[mm] : 1.f;
          if (prem) val *= mv;
          val = (val + bn) * scale;
          if (relu) val = fmaxf(val, 0.f);
          if (postm) val *= mv;
          if (bf16o) Yh[(size_t)mm * N + nn] = f2bf(val);
          else       Yf[(size_t)mm * N + nn] = val;
        }
      }
    }
}

// ---------------------------------------------------------------------------
// 128m x 64n tile split-K GEMM, raw fp32 partials only (o-proj / FFN2).
// 4 waves as 2x2 over (128, 64): wave = 64m x 32n = 4x2 MFMA tiles.
// ---------------------------------------------------------------------------
__global__ __launch_bounds__(256) void mfma_gemm64(
    const unsigned short* __restrict__ A, const unsigned short* __restrict__ B,
    float* __restrict__ Y, int M, int N, int K, int lda, int ldb,
    long long kofs, long long sYb)
{
  const int tid = threadIdx.x;
  const int w = tid >> 6, lane = tid & 63;
  const int wm = w >> 1, wn = w & 1;
  const int m0 = blockIdx.y * 128, n0 = blockIdx.x * 64;
  const size_t ko = (size_t)blockIdx.z * kofs;

  __shared__ unsigned short sA[128 * 32];
  __shared__ unsigned short sB[64 * 32];

  floatx4 acc[4][2];
#pragma unroll
  for (int i = 0; i < 4; i++)
#pragma unroll
    for (int j = 0; j < 2; j++) acc[i][j] = floatx4{0.f, 0.f, 0.f, 0.f};

  const int srow = lane >> 2;
  const int skel = (lane & 3) * 8;
  const int col = lane & 15, gq = lane >> 4;

  for (int k0 = 0; k0 < K; k0 += 32) {
    async_copy16(&A[(size_t)(m0 + w * 16 + srow) * lda + ko + k0 + skel],
                 &sA[w * 512]);
    async_copy16(&A[(size_t)(m0 + (w + 4) * 16 + srow) * lda + ko + k0 + skel],
                 &sA[(w + 4) * 512]);
    async_copy16(&B[(size_t)(n0 + w * 16 + srow) * ldb + ko + k0 + skel],
                 &sB[w * 512]);
    __syncthreads();

    short8 af[4], bfr[2];
#pragma unroll
    for (int im = 0; im < 4; im++)
      af[im] = *(const short8*)&sA[(wm * 64 + im * 16 + col) * 32 + gq * 8];
#pragma unroll
    for (int in = 0; in < 2; in++)
      bfr[in] = *(const short8*)&sB[(wn * 32 + in * 16 + col) * 32 + gq * 8];
#pragma unroll
    for (int im = 0; im < 4; im++)
#pragma unroll
      for (int in = 0; in < 2; in++)
        acc[im][in] = MFMA16(af[im], bfr[in], acc[im][in]);
    __syncthreads();
  }

  float* Yf = Y + (size_t)blockIdx.z * sYb;
#pragma unroll
  for (int im = 0; im < 4; im++)
#pragma unroll
    for (int in = 0; in < 2; in++) {
      int nn = n0 + wn * 32 + in * 16 + col;
#pragma unroll
      for (int reg = 0; reg < 4; reg++) {
        int mm = m0 + wm * 64 + im * 16 + gq * 4 + reg;
        Yf[(size_t)mm * N + nn] = acc[im][in][reg];
      }
    }
}

// ---------------------------------------------------------------------------
// Fused QKV GEMM: A = x bf16 (MT x 512), B = [wq;wk;wv] bf16 (1536 x 512).
// Q scale 0.125. Q,K out bf16 (B,T,C); V out bf16 (B,C,T) (fused transpose).
// ---------------------------------------------------------------------------
__global__ __launch_bounds__(256) void qkv_gemm(
    const unsigned short* __restrict__ A, const unsigned short* __restrict__ B,
    unsigned short* __restrict__ qo, unsigned short* __restrict__ ko2,
    unsigned short* __restrict__ vo, const float* __restrict__ qb,
    const float* __restrict__ kb, const float* __restrict__ vb)
{
  const int tid = threadIdx.x;
  const int w = tid >> 6, lane = tid & 63;
  const int wm = w >> 1, wn = w & 1;
  const int m0 = blockIdx.y * 128, n0 = blockIdx.x * 128;

  __shared__ unsigned short sA[128 * 32];
  __shared__ unsigned short sB[128 * 32];

  floatx4 acc[4][4];
#pragma unroll
  for (int i = 0; i < 4; i++)
#pragma unroll
    for (int j = 0; j < 4; j++) acc[i][j] = floatx4{0.f, 0.f, 0.f, 0.f};

  const int srow = lane >> 2;
  const int skel = (lane & 3) * 8;
  const int col = lane & 15, gq = lane >> 4;

  for (int k0 = 0; k0 < CQ; k0 += 32) {
#pragma unroll
    for (int r = 0; r < 2; r++) {
      int c = r * 4 + w;
      async_copy16(&A[(size_t)(m0 + c * 16 + srow) * CQ + k0 + skel],
                   &sA[c * 512]);
      async_copy16(&B[(size_t)(n0 + c * 16 + srow) * CQ + k0 + skel],
                   &sB[c * 512]);
    }
    __syncthreads();

    short8 af[4], bfr[4];
#pragma unroll
    for (int im = 0; im < 4; im++)
      af[im] = *(const short8*)&sA[(wm * 64 + im * 16 + col) * 32 + gq * 8];
#pragma unroll
    for (int in = 0; in < 4; in++)
      bfr[in] = *(const short8*)&sB[(wn * 64 + in * 16 + col) * 32 + gq * 8];
#pragma unroll
    for (int im = 0; im < 4; im++)
#pragma unroll
      for (int in = 0; in < 4; in++)
        acc[im][in] = MFMA16(af[im], bfr[in], acc[im][in]);
    __syncthreads();
  }

  const int seg = n0 >> 9;
  const int nbase = n0 - seg * 512;

  if (seg < 2) {
    unsigned short* Yh = (seg == 0) ? qo : ko2;
    const float* bp = (seg == 0) ? qb : kb;
    const float scale = (seg == 0) ? 0.125f : 1.f;
#pragma unroll
    for (int im = 0; im < 4; im++)
#pragma unroll
      for (int in = 0; in < 4; in++) {
        int nn = nbase + wn * 64 + in * 16 + col;
        float bn = bp[nn];
#pragma unroll
        for (int reg = 0; reg < 4; reg++) {
          int mm = m0 + wm * 64 + im * 16 + gq * 4 + reg;
          Yh[(size_t)mm * CQ + nn] = f2bf((acc[im][in][reg] + bn) * scale);
        }
      }
  } else {
    // V: write (B,C,T) transposed; 4 consecutive t per lane -> ushort4
#pragma unroll
    for (int im = 0; im < 4; im++)
#pragma unroll
      for (int in = 0; in < 4; in++) {
        int nn = nbase + wn * 64 + in * 16 + col;
        float bn = vb[nn];
        int mm0 = m0 + wm * 64 + im * 16 + gq * 4;
        int bz = mm0 >> 10, t = mm0 & 1023;
        ushort4 uv = {f2bf(acc[im][in][0] + bn), f2bf(acc[im][in][1] + bn),
                      f2bf(acc[im][in][2] + bn), f2bf(acc[im][in][3] + bn)};
        *(ushort4*)&vo[((size_t)bz * CQ + nn) * TQ + t] = uv;
      }
  }
}

// ---------------------------------------------------------------------------
// MFMA flash attention, fixed-origin softmax, register-prefetch pipeline.
// Block = 64 Q rows (wave w owns rows i0..i0+15), serial over 16 j-tiles of
// 64, double-buffered K/V/mask register prefetch hides global latency.
// q,k bf16 (B,T,C); v bf16 (B,C,T); o bf16 (B,T,C).
// ---------------------------------------------------------------------------
#define ATTN_PREFETCH(t, kbuf, vbuf, mbuf)                                    \
  do {                                                                        \
    const int _j0 = (t) * 64;                                                 \
    _Pragma("unroll")                                                         \
    for (int _jg = 0; _jg < 4; _jg++) {                                       \
      const size_t _kr = (size_t)(_j0 + _jg * 16 + col) * CQ;                 \
      kbuf[_jg][0] = *(const short8*)&kb[_kr + g * 8];                        \
      kbuf[_jg][1] = *(const short8*)&kb[_kr + 32 + g * 8];                   \
      mbuf[_jg] = mask[(size_t)b * TQ + _j0 + _jg * 16 + col];                \
    }                                                                         \
    _Pragma("unroll")                                                         \
    for (int _dg = 0; _dg < 4; _dg++) {                                       \
      const size_t _vr = (size_t)(_dg * 16 + col) * TQ + _j0;                 \
      vbuf[_dg][0] = *(const short8*)&vb[_vr + g * 8];                        \
      vbuf[_dg][1] = *(const short8*)&vb[_vr + 32 + g * 8];                   \
    }                                                                         \
  } while (0)

__global__ __launch_bounds__(256, 2) void attn_kernel(
    const unsigned short* __restrict__ qt, const unsigned short* __restrict__ kt,
    const unsigned short* __restrict__ vt, const float* __restrict__ mask,
    const float* __restrict__ rk, const float* __restrict__ rv,
    unsigned short* __restrict__ o)
{
  const int b = blockIdx.z, h = blockIdx.y;
  const int w = threadIdx.x >> 6;
  const int lane = threadIdx.x & 63;
  const int col = lane & 15, g = lane >> 4;
  const int i0 = blockIdx.x * 64 + w * 16;

  const unsigned short* qb = qt + (size_t)b * TQ * CQ + h * 64;
  const unsigned short* kb = kt + (size_t)b * TQ * CQ + h * 64;
  const unsigned short* vb = vt + ((size_t)b * CQ + h * 64) * TQ;
  unsigned short* ob = o + (size_t)b * TQ * CQ + h * 64;

  __shared__ unsigned short pbuf[4][16][72];
  __shared__ float rkdl[4][16][9];
  __shared__ float pband[4][16][9];

  short8 qf0 = *(const short8*)&qb[(size_t)(i0 + col) * CQ + g * 8];
  short8 qf1 = *(const short8*)&qb[(size_t)(i0 + col) * CQ + 32 + g * 8];

  // rkd[i][delta] = q_i . rk_delta via MFMA
  {
    short8 rb0 = {0, 0, 0, 0, 0, 0, 0, 0}, rb1 = rb0;
    if (col < 9) {
#pragma unroll
      for (int i = 0; i < 8; i++) {
        rb0[i] = (short)f2bf(rk[col * 64 + g * 8 + i]);
        rb1[i] = (short)f2bf(rk[col * 64 + 32 + g * 8 + i]);
      }
    }
    floatx4 rc = {0.f, 0.f, 0.f, 0.f};
    rc = MFMA16(qf0, rb0, rc);
    rc = MFMA16(qf1, rb1, rc);
    if (col < 9) {
#pragma unroll
      for (int reg = 0; reg < 4; reg++) rkdl[w][g * 4 + reg][col] = rc[reg];
    }
  }
  for (int e = lane; e < 144; e += 64) pband[w][e / 9][e % 9] = 0.f;
  __builtin_amdgcn_wave_barrier();

  float l_lane[4] = {0.f, 0.f, 0.f, 0.f};
  floatx4 oacc[4];
#pragma unroll
  for (int r = 0; r < 4; r++) oacc[r] = floatx4{0.f, 0.f, 0.f, 0.f};

  short8 kf[2][4][2], vf[2][4][2];
  float mv[2][4];
  ATTN_PREFETCH(0, kf[0], vf[0], mv[0]);

#pragma unroll
  for (int jt = 0; jt < 16; jt++) {
    const int cur = jt & 1, nx = cur ^ 1;
    if (jt < 15) ATTN_PREFETCH(jt + 1, kf[nx], vf[nx], mv[nx]);
    const int j0 = jt * 64;

    // ---- S = Q K^T from prefetched K ----
    floatx4 sc[4];
#pragma unroll
    for (int jg = 0; jg < 4; jg++) {
      floatx4 z = {0.f, 0.f, 0.f, 0.f};
      z = MFMA16(qf0, kf[cur][jg][0], z);
      sc[jg] = MFMA16(qf1, kf[cur][jg][1], z);
    }

    const bool inband = (j0 <= i0 + 19) && (j0 + 63 >= i0 - 4);

    float p[4][4];
#pragma unroll
    for (int reg = 0; reg < 4; reg++) {
      const int ig = i0 + g * 4 + reg;
#pragma unroll
      for (int jg = 0; jg < 4; jg++) {
        float s = sc[jg][reg];
        if (inband) {
          int dlt = j0 + jg * 16 + col - ig + 4;
          if (dlt >= 0 && dlt < 9) s += rkdl[w][g * 4 + reg][dlt];
        }
        float pv = (mv[cur][jg] == 0.f) ? 0.f : __expf(s);
        p[reg][jg] = pv;
        l_lane[reg] += pv;
      }
    }

    if (inband) {
#pragma unroll
      for (int reg = 0; reg < 4; reg++) {
        const int row = g * 4 + reg;
#pragma unroll
        for (int jg = 0; jg < 4; jg++) {
          int dlt = j0 + jg * 16 + col - (i0 + row) + 4;
          if (dlt >= 0 && dlt < 9) pband[w][row][dlt] = p[reg][jg];
        }
      }
    }

    // ---- P -> LDS (C-layout) -> A-layout fragments ----
#pragma unroll
    for (int reg = 0; reg < 4; reg++)
#pragma unroll
      for (int jg = 0; jg < 4; jg++)
        pbuf[w][g * 4 + reg][jg * 16 + col] = f2bf(p[reg][jg]);
    __builtin_amdgcn_wave_barrier();
    short8 pf0 = *(const short8*)&pbuf[w][col][g * 8];
    short8 pf1 = *(const short8*)&pbuf[w][col][32 + g * 8];

    // ---- O += P V from prefetched V ----
#pragma unroll
    for (int dg = 0; dg < 4; dg++) {
      oacc[dg] = MFMA16(pf0, vf[cur][dg][0], oacc[dg]);
      oacc[dg] = MFMA16(pf1, vf[cur][dg][1], oacc[dg]);
    }
    __builtin_amdgcn_wave_barrier();
  }

  // ---- row-sum reduction (once) ----
  float inv_l[4];
#pragma unroll
  for (int reg = 0; reg < 4; reg++) {
    float l = l_lane[reg];
#pragma unroll
    for (int off = 1; off < 16; off <<= 1) l += __shfl_xor(l, off, 64);
    inv_l[reg] = 1.f / l;
  }

#pragma unroll
  for (int dg = 0; dg < 4; dg++) {
    float rvc[4] = {0.f, 0.f, 0.f, 0.f};
#pragma unroll
    for (int dlt = 0; dlt < 9; dlt++) {
      float rvv = rv[dlt * 64 + dg * 16 + col];
#pragma unroll
      for (int reg = 0; reg < 4; reg++)
        rvc[reg] += pband[w][g * 4 + reg][dlt] * rvv;
    }
#pragma unroll
    for (int reg = 0; reg < 4; reg++) {
      float val = (oacc[dg][reg] + rvc[reg]) * inv_l[reg];
      ob[(size_t)(i0 + g * 4 + reg) * CQ + dg * 16 + col] = f2bf(val);
    }
  }
}

// ---------------------------------------------------------------------------
// Residual + LayerNorm rows (C=512 contiguous). v = res + s*(a1+a2+addb[c]),
// s = mask if (mode&1). y = LN(v)*g+b; if (mode&2) y *= mask.
// ---------------------------------------------------------------------------
__global__ __launch_bounds__(256) void ln_rows(
    const float* __restrict__ res, const float* __restrict__ a1,
    const float* __restrict__ a2, const float* __restrict__ addb,
    const float* __restrict__ g, const float* __restrict__ bb,
    const float* __restrict__ mask, float* __restrict__ outf,
    unsigned short* __restrict__ outb, int mode)
{
  const int row = blockIdx.x * 4 + (threadIdx.x >> 6);
  const int lane = threadIdx.x & 63;
  const size_t base = (size_t)row * CQ + lane * 8;
  const int c0 = lane * 8;

  float mv = mask[row];
  float sadd = (mode & 1) ? mv : 1.f;

  float v[8];
#pragma unroll
  for (int i = 0; i < 8; i += 4) {
    float4 r = *(const float4*)&res[base + i];
    float4 x1 = *(const float4*)&a1[base + i];
    float4 x2 = *(const float4*)&a2[base + i];
    float4 bv = *(const float4*)&addb[c0 + i];
    v[i + 0] = r.x + sadd * (x1.x + x2.x + bv.x);
    v[i + 1] = r.y + sadd * (x1.y + x2.y + bv.y);
    v[i + 2] = r.z + sadd * (x1.z + x2.z + bv.z);
    v[i + 3] = r.w + sadd * (x1.w + x2.w + bv.w);
  }
  float sum = 0.f, ssq = 0.f;
#pragma unroll
  for (int i = 0; i < 8; i++) { sum += v[i]; ssq += v[i] * v[i]; }
#pragma unroll
  for (int off = 1; off < 64; off <<= 1) {
    sum += __shfl_xor(sum, off, 64);
    ssq += __shfl_xor(ssq, off, 64);
  }
  float mean = sum * (1.f / CQ);
  float var = ssq * (1.f / CQ) - mean * mean;
  float rstd = rsqrtf(var + 1e-6f);
  float pm = (mode & 2) ? mv : 1.f;

  float y[8];
#pragma unroll
  for (int i = 0; i < 8; i++)
    y[i] = ((v[i] - mean) * rstd * g[c0 + i] + bb[c0 + i]) * pm;
  float4 o0 = {y[0], y[1], y[2], y[3]}, o1 = {y[4], y[5], y[6], y[7]};
  *(float4*)&outf[base] = o0;
  *(float4*)&outf[base + 4] = o1;
  if (outb) {
    ushort4 u0 = {f2bf(y[0]), f2bf(y[1]), f2bf(y[2]), f2bf(y[3])};
    ushort4 u1 = {f2bf(y[4]), f2bf(y[5]), f2bf(y[6]), f2bf(y[7])};
    *(ushort4*)&outb[base] = u0;
    *(ushort4*)&outb[base + 4] = u1;
  }
}

// ---------------------------------------------------------------------------
// Transpose-in: x (B,C,T) fp32 -> xa fp32 (B,T,C) + xab bf16 (B,T,C)
// ---------------------------------------------------------------------------
__global__ __launch_bounds__(256) void tr_in(
    const float* __restrict__ x, float* __restrict__ xa,
    unsigned short* __restrict__ xab)
{
  __shared__ float s[32][33];
  const int b = blockIdx.z, t0 = blockIdx.x * 32, c0 = blockIdx.y * 32;
  const int tx = threadIdx.x, ty = threadIdx.y;
#pragma unroll
  for (int r = 0; r < 4; r++)
    s[ty + r * 8][tx] = x[((size_t)b * CQ + c0 + ty + r * 8) * TQ + t0 + tx];
  __syncthreads();
#pragma unroll
  for (int r = 0; r < 4; r++) {
    float v = s[tx][ty + r * 8];
    size_t idx = ((size_t)b * TQ + t0 + ty + r * 8) * CQ + c0 + tx;
    xa[idx] = v;
    xab[idx] = f2bf(v);
  }
}

// ---------------------------------------------------------------------------
// Transpose-out: y (B,T,C) fp32 -> out (B,C,T) fp32
// ---------------------------------------------------------------------------
__global__ __launch_bounds__(256) void tr_out(
    const float* __restrict__ y, float* __restrict__ out)
{
  __shared__ float s[32][33];
  const int b = blockIdx.z, t0 = blockIdx.x * 32, c0 = blockIdx.y * 32;
  const int tx = threadIdx.x, ty = threadIdx.y;
#pragma unroll
  for (int r = 0; r < 4; r++)
    s[ty + r * 8][tx] = y[((size_t)b * TQ + t0 + ty + r * 8) * CQ + c0 + tx];
  __syncthreads();
#pragma unroll
  for (int r = 0; r < 4; r++)
    out[((size_t)b * CQ + c0 + ty + r * 8) * TQ + t0 + tx] = s[tx][ty + r * 8];
}

// ---------------------------------------------------------------------------
// Per-layer weight fp32 -> bf16 (layouts contiguous: fused QKV = rows 0..1535)
// ---------------------------------------------------------------------------
__global__ __launch_bounds__(256) void wconv(
    const float* __restrict__ qw, const float* __restrict__ kw,
    const float* __restrict__ vw, const float* __restrict__ ow,
    const float* __restrict__ w1, const float* __restrict__ w2,
    unsigned short* __restrict__ dst)
{
  int idx4 = blockIdx.x * 256 + threadIdx.x;
  int i = idx4 * 4;
  const float* src;
  int off;
  if (i < 1048576) {
    int which = i >> 18;
    src = (which == 0) ? qw : (which == 1) ? kw : (which == 2) ? vw : ow;
    off = i & 262143;
  } else if (i < 2097152) {
    src = w1; off = i - 1048576;
  } else {
    src = w2; off = i - 2097152;
  }
  float4 v = *(const float4*)&src[off];
  ushort4 u = {f2bf(v.x), f2bf(v.y), f2bf(v.z), f2bf(v.w)};
  *(ushort4*)&dst[i] = u;
}

// ---------------------------------------------------------------------------
extern "C" void kernel_launch(void* const* d_in, const int* in_sizes, int n_in,
                              void* d_out, int out_size, void* d_ws, size_t ws_size,
                              hipStream_t stream) {
  const float* x    = (const float*)d_in[0];
  const float* mask = (const float*)d_in[1];
  const float* qw   = (const float*)d_in[2];
  const float* qbb  = (const float*)d_in[3];
  const float* kw   = (const float*)d_in[4];
  const float* kbb  = (const float*)d_in[5];
  const float* vw   = (const float*)d_in[6];
  const float* vbb  = (const float*)d_in[7];
  const float* ow   = (const float*)d_in[8];
  const float* obb  = (const float*)d_in[9];
  const float* rk   = (const float*)d_in[10];
  const float* rv   = (const float*)d_in[11];
  const float* g1   = (const float*)d_in[12];
  const float* be1  = (const float*)d_in[13];
  const float* w1   = (const float*)d_in[14];
  const float* b1   = (const float*)d_in[15];
  const float* w2   = (const float*)d_in[16];
  const float* b2   = (const float*)d_in[17];
  const float* g2   = (const float*)d_in[18];
  const float* be2  = (const float*)d_in[19];
  float* out = (float*)d_out;

  const size_t MB = 1 << 20;
  char* base = (char*)d_ws;
  unsigned short* wbuf  = (unsigned short*)(base);            // 6 MB
  float*          xa    = (float*)(base + 6 * MB);            // 8 MB fp32 (B,T,C)
  unsigned short* xab   = (unsigned short*)(base + 14 * MB);  // 4 MB bf16 (B,T,C)
  unsigned short* qtb   = (unsigned short*)(base + 18 * MB);  // 4 MB
  unsigned short* ktb   = (unsigned short*)(base + 22 * MB);  // 4 MB
  unsigned short* vtb   = (unsigned short*)(base + 30 * MB);  // 4 MB (B,C,T)
  unsigned short* obufb = (unsigned short*)(base + 34 * MB);  // 4 MB (B,T,C)
  float*          t1    = (float*)(base + 38 * MB);           // 8 MB fp32
  // t1b = t1 + MT*CQ (contiguous @46 MB, 8 MB) -- split-K partial 2
  unsigned short* hbuf  = qtb;   // FFN hidden bf16 (B,T,F): 16 MB over 18..34

  const unsigned short* wo  = wbuf + 786432;
  const unsigned short* wf1 = wbuf + 1048576;
  const unsigned short* wf2 = wbuf + 2097152;
  const long long sY = (long long)MT * CQ;
  float* t1b = t1 + sY;

  dim3 b256(256);
  dim3 gtr(TQ / 32, CQ / 32, BQ);
  dim3 gln(MT / 4);

  hipLaunchKernelGGL(tr_in, gtr, dim3(32, 8), 0, stream, x, xa, xab);

  for (int i = 0; i < LQ; i++) {
    hipLaunchKernelGGL(wconv, dim3(3072), b256, 0, stream,
        qw + (size_t)i * CQ * CQ, kw + (size_t)i * CQ * CQ,
        vw + (size_t)i * CQ * CQ, ow + (size_t)i * CQ * CQ,
        w1 + (size_t)i * FQ * CQ, w2 + (size_t)i * CQ * FQ, wbuf);
    // fused QKV: (4096 x 1536), V written transposed (B,C,T); 384 blocks
    hipLaunchKernelGGL(qkv_gemm, dim3(12, 32), b256, 0, stream,
        xab, wbuf, qtb, ktb, vtb, qbb + i * CQ, kbb + i * CQ, vbb + i * CQ);
    // attention: 64 Q rows/block, register-prefetch pipeline (512 blocks)
    hipLaunchKernelGGL(attn_kernel, dim3(TQ / 64, HQ, BQ), b256, 0, stream,
        qtb, ktb, vtb, mask, rk + (size_t)i * 576, rv + (size_t)i * 576, obufb);
    // o-proj split-K=2, 128x64 tiles -> 512 blocks, raw partials t1/t1b
    hipLaunchKernelGGL(mfma_gemm64, dim3(8, 32, 2), b256, 0, stream,
        obufb, wo, t1, MT, CQ, CQ / 2, CQ, CQ, (long long)(CQ / 2), sY);
    hipLaunchKernelGGL(ln_rows, gln, b256, 0, stream,
        xa, t1, t1b, obb + i * CQ, g1 + i * CQ, be1 + i * CQ, mask,
        xa, xab, 0);
    // FFN1 (512 blocks): premask+relu+postmask, bf16 out
    hipLaunchKernelGGL(mfma_gemm, dim3(16, 32, 1), b256, 0, stream,
        xab, wf1, (void*)hbuf, b1 + i * FQ, mask,
        MT, FQ, CQ, CQ, CQ, 0LL, 0LL, 1.f, 1 | 2 | 4 | 16);
    // FFN2 split-K=2, 128x64 tiles -> 512 blocks, raw partials
    hipLaunchKernelGGL(mfma_gemm64, dim3(8, 32, 2), b256, 0, stream,
        hbuf, wf2, t1, MT, CQ, FQ / 2, FQ, FQ, (long long)(FQ / 2), sY);
    hipLaunchKernelGGL(ln_rows, gln, b256, 0, stream,
        xa, t1, t1b, b2 + i * CQ, g2 + i * CQ, be2 + i * CQ, mask,
        xa, xab, 3);
  }
  hipLaunchKernelGGL(tr_out, gtr, dim3(32, 8), 0, stream, xa, out);
}

// Round 8
// 678.243 us; speedup vs baseline: 1.3359x; 1.3359x over previous
//
#include <hip/hip_runtime.h>

#define BQ 4
#define CQ 512
#define TQ 1024
#define FQ 2048
#define LQ 4
#define HQ 8
#define MT (BQ * TQ)            // batch-folded rows = 4096

typedef __attribute__((ext_vector_type(8))) short short8;
typedef __attribute__((ext_vector_type(4))) float floatx4;

#define MFMA16(a, b, c) __builtin_amdgcn_mfma_f32_16x16x32_bf16(a, b, c, 0, 0, 0)

static __device__ __forceinline__ unsigned short f2bf(float f) {
  union { float f; unsigned u; } v; v.f = f;
  unsigned r = v.u + 0x7fff + ((v.u >> 16) & 1);
  return (unsigned short)(r >> 16);
}

static __device__ __forceinline__ void async_copy16(const void* g, void* l) {
  __builtin_amdgcn_global_load_lds(
      (const __attribute__((address_space(1))) void*)g,
      (__attribute__((address_space(3))) void*)l, 16, 0, 0);
}

// ---------------------------------------------------------------------------
// bf16 MFMA GEMM: Y[m,n] = epi( sum_k A[m, ko+k] B[n, ko+k] ), ko = z*kofs
// 128x128 tile, BK=32, 4 waves (2x2). flags: 1=relu 2=premask(row m)
// 4=postmask(row m) 16=bf16 out 32=raw fp32 (split-K partial, Y += z*sYb)
// ---------------------------------------------------------------------------
__global__ __launch_bounds__(256) void mfma_gemm(
    const unsigned short* __restrict__ A, const unsigned short* __restrict__ B,
    void* __restrict__ Y, const float* __restrict__ bias,
    const float* __restrict__ mask, int M, int N, int K, int lda, int ldb,
    long long kofs, long long sYb, float scale, int flags)
{
  const int tid = threadIdx.x;
  const int w = tid >> 6, lane = tid & 63;
  const int wm = w >> 1, wn = w & 1;
  const int m0 = blockIdx.y * 128, n0 = blockIdx.x * 128;
  const size_t ko = (size_t)blockIdx.z * kofs;

  __shared__ unsigned short sA[128 * 32];
  __shared__ unsigned short sB[128 * 32];

  floatx4 acc[4][4];
#pragma unroll
  for (int i = 0; i < 4; i++)
#pragma unroll
    for (int j = 0; j < 4; j++) acc[i][j] = floatx4{0.f, 0.f, 0.f, 0.f};

  const int srow = lane >> 2;
  const int skel = (lane & 3) * 8;
  const int col = lane & 15, gq = lane >> 4;

  for (int k0 = 0; k0 < K; k0 += 32) {
#pragma unroll
    for (int r = 0; r < 2; r++) {
      int c = r * 4 + w;
      async_copy16(&A[(size_t)(m0 + c * 16 + srow) * lda + ko + k0 + skel],
                   &sA[c * 512]);
      async_copy16(&B[(size_t)(n0 + c * 16 + srow) * ldb + ko + k0 + skel],
                   &sB[c * 512]);
    }
    __syncthreads();

    short8 af[4], bfr[4];
#pragma unroll
    for (int im = 0; im < 4; im++)
      af[im] = *(const short8*)&sA[(wm * 64 + im * 16 + col) * 32 + gq * 8];
#pragma unroll
    for (int in = 0; in < 4; in++)
      bfr[in] = *(const short8*)&sB[(wn * 64 + in * 16 + col) * 32 + gq * 8];
#pragma unroll
    for (int im = 0; im < 4; im++)
#pragma unroll
      for (int in = 0; in < 4; in++)
        acc[im][in] = MFMA16(af[im], bfr[in], acc[im][in]);
    __syncthreads();
  }

  const bool relu  = flags & 1;
  const bool prem  = flags & 2;
  const bool postm = flags & 4;
  const bool bf16o = flags & 16;
  const bool raw   = flags & 32;
  float* Yf = (float*)Y + (size_t)blockIdx.z * sYb;
  unsigned short* Yh = (unsigned short*)Y;

#pragma unroll
  for (int im = 0; im < 4; im++)
#pragma unroll
    for (int in = 0; in < 4; in++) {
      int nn = n0 + wn * 64 + in * 16 + col;
      float bn = raw ? 0.f : bias[nn];
#pragma unroll
      for (int reg = 0; reg < 4; reg++) {
        int mm = m0 + wm * 64 + im * 16 + gq * 4 + reg;
        float val = acc[im][in][reg];
        if (raw) {
          Yf[(size_t)mm * N + nn] = val;
        } else {
          float mv = (prem || postm) ? mask[mm] : 1.f;
          if (prem) val *= mv;
          val = (val + bn) * scale;
          if (relu) val = fmaxf(val, 0.f);
          if (postm) val *= mv;
          if (bf16o) Yh[(size_t)mm * N + nn] = f2bf(val);
          else       Yf[(size_t)mm * N + nn] = val;
        }
      }
    }
}

// ---------------------------------------------------------------------------
// 128m x 64n tile split-K GEMM, raw fp32 partials only (o-proj / FFN2).
// ---------------------------------------------------------------------------
__global__ __launch_bounds__(256) void mfma_gemm64(
    const unsigned short* __restrict__ A, const unsigned short* __restrict__ B,
    float* __restrict__ Y, int M, int N, int K, int lda, int ldb,
    long long kofs, long long sYb)
{
  const int tid = threadIdx.x;
  const int w = tid >> 6, lane = tid & 63;
  const int wm = w >> 1, wn = w & 1;
  const int m0 = blockIdx.y * 128, n0 = blockIdx.x * 64;
  const size_t ko = (size_t)blockIdx.z * kofs;

  __shared__ unsigned short sA[128 * 32];
  __shared__ unsigned short sB[64 * 32];

  floatx4 acc[4][2];
#pragma unroll
  for (int i = 0; i < 4; i++)
#pragma unroll
    for (int j = 0; j < 2; j++) acc[i][j] = floatx4{0.f, 0.f, 0.f, 0.f};

  const int srow = lane >> 2;
  const int skel = (lane & 3) * 8;
  const int col = lane & 15, gq = lane >> 4;

  for (int k0 = 0; k0 < K; k0 += 32) {
    async_copy16(&A[(size_t)(m0 + w * 16 + srow) * lda + ko + k0 + skel],
                 &sA[w * 512]);
    async_copy16(&A[(size_t)(m0 + (w + 4) * 16 + srow) * lda + ko + k0 + skel],
                 &sA[(w + 4) * 512]);
    async_copy16(&B[(size_t)(n0 + w * 16 + srow) * ldb + ko + k0 + skel],
                 &sB[w * 512]);
    __syncthreads();

    short8 af[4], bfr[2];
#pragma unroll
    for (int im = 0; im < 4; im++)
      af[im] = *(const short8*)&sA[(wm * 64 + im * 16 + col) * 32 + gq * 8];
#pragma unroll
    for (int in = 0; in < 2; in++)
      bfr[in] = *(const short8*)&sB[(wn * 32 + in * 16 + col) * 32 + gq * 8];
#pragma unroll
    for (int im = 0; im < 4; im++)
#pragma unroll
      for (int in = 0; in < 2; in++)
        acc[im][in] = MFMA16(af[im], bfr[in], acc[im][in]);
    __syncthreads();
  }

  float* Yf = Y + (size_t)blockIdx.z * sYb;
#pragma unroll
  for (int im = 0; im < 4; im++)
#pragma unroll
    for (int in = 0; in < 2; in++) {
      int nn = n0 + wn * 32 + in * 16 + col;
#pragma unroll
      for (int reg = 0; reg < 4; reg++) {
        int mm = m0 + wm * 64 + im * 16 + gq * 4 + reg;
        Yf[(size_t)mm * N + nn] = acc[im][in][reg];
      }
    }
}

// ---------------------------------------------------------------------------
// Fused QKV GEMM: A = x bf16 (MT x 512), B = [wq;wk;wv] bf16 (1536 x 512).
// Q scale 0.125. Q,K out bf16 (B,T,C); V out bf16 (B,C,T) (fused transpose).
// ---------------------------------------------------------------------------
__global__ __launch_bounds__(256) void qkv_gemm(
    const unsigned short* __restrict__ A, const unsigned short* __restrict__ B,
    unsigned short* __restrict__ qo, unsigned short* __restrict__ ko2,
    unsigned short* __restrict__ vo, const float* __restrict__ qb,
    const float* __restrict__ kb, const float* __restrict__ vb)
{
  const int tid = threadIdx.x;
  const int w = tid >> 6, lane = tid & 63;
  const int wm = w >> 1, wn = w & 1;
  const int m0 = blockIdx.y * 128, n0 = blockIdx.x * 128;

  __shared__ unsigned short sA[128 * 32];
  __shared__ unsigned short sB[128 * 32];

  floatx4 acc[4][4];
#pragma unroll
  for (int i = 0; i < 4; i++)
#pragma unroll
    for (int j = 0; j < 4; j++) acc[i][j] = floatx4{0.f, 0.f, 0.f, 0.f};

  const int srow = lane >> 2;
  const int skel = (lane & 3) * 8;
  const int col = lane & 15, gq = lane >> 4;

  for (int k0 = 0; k0 < CQ; k0 += 32) {
#pragma unroll
    for (int r = 0; r < 2; r++) {
      int c = r * 4 + w;
      async_copy16(&A[(size_t)(m0 + c * 16 + srow) * CQ + k0 + skel],
                   &sA[c * 512]);
      async_copy16(&B[(size_t)(n0 + c * 16 + srow) * CQ + k0 + skel],
                   &sB[c * 512]);
    }
    __syncthreads();

    short8 af[4], bfr[4];
#pragma unroll
    for (int im = 0; im < 4; im++)
      af[im] = *(const short8*)&sA[(wm * 64 + im * 16 + col) * 32 + gq * 8];
#pragma unroll
    for (int in = 0; in < 4; in++)
      bfr[in] = *(const short8*)&sB[(wn * 64 + in * 16 + col) * 32 + gq * 8];
#pragma unroll
    for (int im = 0; im < 4; im++)
#pragma unroll
      for (int in = 0; in < 4; in++)
        acc[im][in] = MFMA16(af[im], bfr[in], acc[im][in]);
    __syncthreads();
  }

  const int seg = n0 >> 9;
  const int nbase = n0 - seg * 512;

  if (seg < 2) {
    unsigned short* Yh = (seg == 0) ? qo : ko2;
    const float* bp = (seg == 0) ? qb : kb;
    const float scale = (seg == 0) ? 0.125f : 1.f;
#pragma unroll
    for (int im = 0; im < 4; im++)
#pragma unroll
      for (int in = 0; in < 4; in++) {
        int nn = nbase + wn * 64 + in * 16 + col;
        float bn = bp[nn];
#pragma unroll
        for (int reg = 0; reg < 4; reg++) {
          int mm = m0 + wm * 64 + im * 16 + gq * 4 + reg;
          Yh[(size_t)mm * CQ + nn] = f2bf((acc[im][in][reg] + bn) * scale);
        }
      }
  } else {
    // V: write (B,C,T) transposed; 4 consecutive t per lane -> ushort4
#pragma unroll
    for (int im = 0; im < 4; im++)
#pragma unroll
      for (int in = 0; in < 4; in++) {
        int nn = nbase + wn * 64 + in * 16 + col;
        float bn = vb[nn];
        int mm0 = m0 + wm * 64 + im * 16 + gq * 4;
        int bz = mm0 >> 10, t = mm0 & 1023;
        ushort4 uv = {f2bf(acc[im][in][0] + bn), f2bf(acc[im][in][1] + bn),
                      f2bf(acc[im][in][2] + bn), f2bf(acc[im][in][3] + bn)};
        *(ushort4*)&vo[((size_t)bz * CQ + nn) * TQ + t] = uv;
      }
  }
}

// ---------------------------------------------------------------------------
// MFMA flash attention, fixed-origin softmax, m97-style LDS double-buffered
// cooperative K/V staging (global_load_lds w=16, XOR-swizzled 16B blocks).
// Block = 64 Q rows, 4 waves (wave w -> rows i0 = bx*64 + w*16), 16 j-tiles
// of 64. Swizzle: LDS block p of row r holds global block p^(r&7), so
// ds_read_b128 of block (h*4+g)^(col&7) is 2-way-conflict free.
// q,k bf16 (B,T,C); v bf16 (B,C,T); o bf16 (B,T,C).
// ---------------------------------------------------------------------------
__global__ __launch_bounds__(256) void attn_kernel(
    const unsigned short* __restrict__ qt, const unsigned short* __restrict__ kt,
    const unsigned short* __restrict__ vt, const float* __restrict__ mask,
    const float* __restrict__ rk, const float* __restrict__ rv,
    unsigned short* __restrict__ o)
{
  const int b = blockIdx.z, h = blockIdx.y;
  const int w = threadIdx.x >> 6;
  const int lane = threadIdx.x & 63;
  const int col = lane & 15, g = lane >> 4;
  const int i0 = blockIdx.x * 64 + w * 16;

  const unsigned short* qb = qt + (size_t)b * TQ * CQ + h * 64;
  const unsigned short* kb = kt + (size_t)b * TQ * CQ + h * 64;
  const unsigned short* vb = vt + ((size_t)b * CQ + h * 64) * TQ;
  unsigned short* ob = o + (size_t)b * TQ * CQ + h * 64;

  __shared__ unsigned short sK[2][64 * 64];   // 8 KB x2
  __shared__ unsigned short sV[2][64 * 64];   // 8 KB x2 ([d][j])
  __shared__ unsigned short pbuf[4][16][72];
  __shared__ float rkdl[4][16][9];
  __shared__ float pband[4][16][9];
  __shared__ float smask[TQ];

  short8 qf0 = *(const short8*)&qb[(size_t)(i0 + col) * CQ + g * 8];
  short8 qf1 = *(const short8*)&qb[(size_t)(i0 + col) * CQ + 32 + g * 8];

  // rkd[i][delta] = q_i . rk_delta via MFMA (wave-private)
  {
    short8 rb0 = {0, 0, 0, 0, 0, 0, 0, 0}, rb1 = rb0;
    if (col < 9) {
#pragma unroll
      for (int i = 0; i < 8; i++) {
        rb0[i] = (short)f2bf(rk[col * 64 + g * 8 + i]);
        rb1[i] = (short)f2bf(rk[col * 64 + 32 + g * 8 + i]);
      }
    }
    floatx4 rc = {0.f, 0.f, 0.f, 0.f};
    rc = MFMA16(qf0, rb0, rc);
    rc = MFMA16(qf1, rb1, rc);
    if (col < 9) {
#pragma unroll
      for (int reg = 0; reg < 4; reg++) rkdl[w][g * 4 + reg][col] = rc[reg];
    }
  }
  for (int e = lane; e < 144; e += 64) pband[w][e / 9][e % 9] = 0.f;
  // mask -> LDS (block-cooperative)
  {
    float4 mvv = *(const float4*)&mask[(size_t)b * TQ + threadIdx.x * 4];
    *(float4*)&smask[threadIdx.x * 4] = mvv;
  }

  // staging lane geometry: row chunk = lane>>3, swizzled block = (lane&7)^(lane>>3)
  const int prow = lane >> 3;
  const int pblk = (lane & 7) ^ prow;
  const int eblk0 = ((0 * 4 + g) ^ (col & 7)) * 8;   // read-side k-block offsets
  const int eblk1 = ((1 * 4 + g) ^ (col & 7)) * 8;

  // stage tile 0 into buffer 0: wave w does chunks s = 2w, 2w+1 for K and V
#pragma unroll
  for (int q = 0; q < 2; q++) {
    int s = w * 2 + q;
    async_copy16(&kb[(size_t)(s * 8 + prow) * CQ + pblk * 8], &sK[0][s * 512]);
    async_copy16(&vb[(size_t)(s * 8 + prow) * TQ + 0 + pblk * 8], &sV[0][s * 512]);
  }

  float l_lane[4] = {0.f, 0.f, 0.f, 0.f};
  floatx4 oacc[4];
#pragma unroll
  for (int r = 0; r < 4; r++) oacc[r] = floatx4{0.f, 0.f, 0.f, 0.f};

  for (int jt = 0; jt < 16; jt++) {
    const int cur = jt & 1, nx = cur ^ 1;
    __syncthreads();  // buf[cur] staged (drains vmcnt); buf[nx] free to fill
    if (jt < 15) {
      const int j0n = (jt + 1) * 64;
#pragma unroll
      for (int q = 0; q < 2; q++) {
        int s = w * 2 + q;
        async_copy16(&kb[(size_t)(j0n + s * 8 + prow) * CQ + pblk * 8],
                     &sK[nx][s * 512]);
        async_copy16(&vb[(size_t)(s * 8 + prow) * TQ + j0n + pblk * 8],
                     &sV[nx][s * 512]);
      }
    }
    const int j0 = jt * 64;

    // ---- S = Q K^T from LDS ----
    floatx4 sc[4];
#pragma unroll
    for (int jg = 0; jg < 4; jg++) {
      const int r = (jg * 16 + col) * 64;
      short8 kf0 = *(const short8*)&sK[cur][r + eblk0];
      short8 kf1 = *(const short8*)&sK[cur][r + eblk1];
      floatx4 z = {0.f, 0.f, 0.f, 0.f};
      z = MFMA16(qf0, kf0, z);
      sc[jg] = MFMA16(qf1, kf1, z);
    }

    const bool inband = (j0 <= i0 + 19) && (j0 + 63 >= i0 - 4);

    float p[4][4];
#pragma unroll
    for (int reg = 0; reg < 4; reg++) {
      const int ig = i0 + g * 4 + reg;
#pragma unroll
      for (int jg = 0; jg < 4; jg++) {
        float s = sc[jg][reg];
        if (inband) {
          int dlt = j0 + jg * 16 + col - ig + 4;
          if (dlt >= 0 && dlt < 9) s += rkdl[w][g * 4 + reg][dlt];
        }
        float pv = (smask[j0 + jg * 16 + col] == 0.f) ? 0.f : __expf(s);
        p[reg][jg] = pv;
        l_lane[reg] += pv;
      }
    }

    if (inband) {
#pragma unroll
      for (int reg = 0; reg < 4; reg++) {
        const int row = g * 4 + reg;
#pragma unroll
        for (int jg = 0; jg < 4; jg++) {
          int dlt = j0 + jg * 16 + col - (i0 + row) + 4;
          if (dlt >= 0 && dlt < 9) pband[w][row][dlt] = p[reg][jg];
        }
      }
    }

    // ---- P -> LDS (C-layout) -> A-layout fragments (wave-private) ----
#pragma unroll
    for (int reg = 0; reg < 4; reg++)
#pragma unroll
      for (int jg = 0; jg < 4; jg++)
        pbuf[w][g * 4 + reg][jg * 16 + col] = f2bf(p[reg][jg]);
    __builtin_amdgcn_wave_barrier();
    short8 pf0 = *(const short8*)&pbuf[w][col][g * 8];
    short8 pf1 = *(const short8*)&pbuf[w][col][32 + g * 8];

    // ---- O += P V from LDS ----
#pragma unroll
    for (int dg = 0; dg < 4; dg++) {
      const int r = (dg * 16 + col) * 64;
      short8 vf0 = *(const short8*)&sV[cur][r + eblk0];
      short8 vf1 = *(const short8*)&sV[cur][r + eblk1];
      oacc[dg] = MFMA16(pf0, vf0, oacc[dg]);
      oacc[dg] = MFMA16(pf1, vf1, oacc[dg]);
    }
    __builtin_amdgcn_wave_barrier();
  }

  // ---- row-sum reduction (once) ----
  float inv_l[4];
#pragma unroll
  for (int reg = 0; reg < 4; reg++) {
    float l = l_lane[reg];
#pragma unroll
    for (int off = 1; off < 16; off <<= 1) l += __shfl_xor(l, off, 64);
    inv_l[reg] = 1.f / l;
  }

#pragma unroll
  for (int dg = 0; dg < 4; dg++) {
    float rvc[4] = {0.f, 0.f, 0.f, 0.f};
#pragma unroll
    for (int dlt = 0; dlt < 9; dlt++) {
      float rvv = rv[dlt * 64 + dg * 16 + col];
#pragma unroll
      for (int reg = 0; reg < 4; reg++)
        rvc[reg] += pband[w][g * 4 + reg][dlt] * rvv;
    }
#pragma unroll
    for (int reg = 0; reg < 4; reg++) {
      float val = (oacc[dg][reg] + rvc[reg]) * inv_l[reg];
      ob[(size_t)(i0 + g * 4 + reg) * CQ + dg * 16 + col] = f2bf(val);
    }
  }
}

// ---------------------------------------------------------------------------
// Residual + LayerNorm rows (C=512 contiguous). v = res + s*(a1+a2+addb[c]),
// s = mask if (mode&1). y = LN(v)*g+b; if (mode&2) y *= mask.
// ---------------------------------------------------------------------------
__global__ __launch_bounds__(256) void ln_rows(
    const float* __restrict__ res, const float* __restrict__ a1,
    const float* __restrict__ a2, const float* __restrict__ addb,
    const float* __restrict__ g, const float* __restrict__ bb,
    const float* __restrict__ mask, float* __restrict__ outf,
    unsigned short* __restrict__ outb, int mode)
{
  const int row = blockIdx.x * 4 + (threadIdx.x >> 6);
  const int lane = threadIdx.x & 63;
  const size_t base = (size_t)row * CQ + lane * 8;
  const int c0 = lane * 8;

  float mv = mask[row];
  float sadd = (mode & 1) ? mv : 1.f;

  float v[8];
#pragma unroll
  for (int i = 0; i < 8; i += 4) {
    float4 r = *(const float4*)&res[base + i];
    float4 x1 = *(const float4*)&a1[base + i];
    float4 x2 = *(const float4*)&a2[base + i];
    float4 bv = *(const float4*)&addb[c0 + i];
    v[i + 0] = r.x + sadd * (x1.x + x2.x + bv.x);
    v[i + 1] = r.y + sadd * (x1.y + x2.y + bv.y);
    v[i + 2] = r.z + sadd * (x1.z + x2.z + bv.z);
    v[i + 3] = r.w + sadd * (x1.w + x2.w + bv.w);
  }
  float sum = 0.f, ssq = 0.f;
#pragma unroll
  for (int i = 0; i < 8; i++) { sum += v[i]; ssq += v[i] * v[i]; }
#pragma unroll
  for (int off = 1; off < 64; off <<= 1) {
    sum += __shfl_xor(sum, off, 64);
    ssq += __shfl_xor(ssq, off, 64);
  }
  float mean = sum * (1.f / CQ);
  float var = ssq * (1.f / CQ) - mean * mean;
  float rstd = rsqrtf(var + 1e-6f);
  float pm = (mode & 2) ? mv : 1.f;

  float y[8];
#pragma unroll
  for (int i = 0; i < 8; i++)
    y[i] = ((v[i] - mean) * rstd * g[c0 + i] + bb[c0 + i]) * pm;
  float4 o0 = {y[0], y[1], y[2], y[3]}, o1 = {y[4], y[5], y[6], y[7]};
  *(float4*)&outf[base] = o0;
  *(float4*)&outf[base + 4] = o1;
  if (outb) {
    ushort4 u0 = {f2bf(y[0]), f2bf(y[1]), f2bf(y[2]), f2bf(y[3])};
    ushort4 u1 = {f2bf(y[4]), f2bf(y[5]), f2bf(y[6]), f2bf(y[7])};
    *(ushort4*)&outb[base] = u0;
    *(ushort4*)&outb[base + 4] = u1;
  }
}

// ---------------------------------------------------------------------------
// Transpose-in: x (B,C,T) fp32 -> xa fp32 (B,T,C) + xab bf16 (B,T,C)
// ---------------------------------------------------------------------------
__global__ __launch_bounds__(256) void tr_in(
    const float* __restrict__ x, float* __restrict__ xa,
    unsigned short* __restrict__ xab)
{
  __shared__ float s[32][33];
  const int b = blockIdx.z, t0 = blockIdx.x * 32, c0 = blockIdx.y * 32;
  const int tx = threadIdx.x, ty = threadIdx.y;
#pragma unroll
  for (int r = 0; r < 4; r++)
    s[ty + r * 8][tx] = x[((size_t)b * CQ + c0 + ty + r * 8) * TQ + t0 + tx];
  __syncthreads();
#pragma unroll
  for (int r = 0; r < 4; r++) {
    float v = s[tx][ty + r * 8];
    size_t idx = ((size_t)b * TQ + t0 + ty + r * 8) * CQ + c0 + tx;
    xa[idx] = v;
    xab[idx] = f2bf(v);
  }
}

// ---------------------------------------------------------------------------
// Transpose-out: y (B,T,C) fp32 -> out (B,C,T) fp32
// ---------------------------------------------------------------------------
__global__ __launch_bounds__(256) void tr_out(
    const float* __restrict__ y, float* __restrict__ out)
{
  __shared__ float s[32][33];
  const int b = blockIdx.z, t0 = blockIdx.x * 32, c0 = blockIdx.y * 32;
  const int tx = threadIdx.x, ty = threadIdx.y;
#pragma unroll
  for (int r = 0; r < 4; r++)
    s[ty + r * 8][tx] = y[((size_t)b * TQ + t0 + ty + r * 8) * CQ + c0 + tx];
  __syncthreads();
#pragma unroll
  for (int r = 0; r < 4; r++)
    out[((size_t)b * CQ + c0 + ty + r * 8) * TQ + t0 + tx] = s[tx][ty + r * 8];
}

// ---------------------------------------------------------------------------
// Per-layer weight fp32 -> bf16 (layouts contiguous: fused QKV = rows 0..1535)
// ---------------------------------------------------------------------------
__global__ __launch_bounds__(256) void wconv(
    const float* __restrict__ qw, const float* __restrict__ kw,
    const float* __restrict__ vw, const float* __restrict__ ow,
    const float* __restrict__ w1, const float* __restrict__ w2,
    unsigned short* __restrict__ dst)
{
  int idx4 = blockIdx.x * 256 + threadIdx.x;
  int i = idx4 * 4;
  const float* src;
  int off;
  if (i < 1048576) {
    int which = i >> 18;
    src = (which == 0) ? qw : (which == 1) ? kw : (which == 2) ? vw : ow;
    off = i & 262143;
  } else if (i < 2097152) {
    src = w1; off = i - 1048576;
  } else {
    src = w2; off = i - 2097152;
  }
  float4 v = *(const float4*)&src[off];
  ushort4 u = {f2bf(v.x), f2bf(v.y), f2bf(v.z), f2bf(v.w)};
  *(ushort4*)&dst[i] = u;
}

// ---------------------------------------------------------------------------
extern "C" void kernel_launch(void* const* d_in, const int* in_sizes, int n_in,
                              void* d_out, int out_size, void* d_ws, size_t ws_size,
                              hipStream_t stream) {
  const float* x    = (const float*)d_in[0];
  const float* mask = (const float*)d_in[1];
  const float* qw   = (const float*)d_in[2];
  const float* qbb  = (const float*)d_in[3];
  const float* kw   = (const float*)d_in[4];
  const float* kbb  = (const float*)d_in[5];
  const float* vw   = (const float*)d_in[6];
  const float* vbb  = (const float*)d_in[7];
  const float* ow   = (const float*)d_in[8];
  const float* obb  = (const float*)d_in[9];
  const float* rk   = (const float*)d_in[10];
  const float* rv   = (const float*)d_in[11];
  const float* g1   = (const float*)d_in[12];
  const float* be1  = (const float*)d_in[13];
  const float* w1   = (const float*)d_in[14];
  const float* b1   = (const float*)d_in[15];
  const float* w2   = (const float*)d_in[16];
  const float* b2   = (const float*)d_in[17];
  const float* g2   = (const float*)d_in[18];
  const float* be2  = (const float*)d_in[19];
  float* out = (float*)d_out;

  const size_t MB = 1 << 20;
  char* base = (char*)d_ws;
  unsigned short* wbuf  = (unsigned short*)(base);            // 6 MB
  float*          xa    = (float*)(base + 6 * MB);            // 8 MB fp32 (B,T,C)
  unsigned short* xab   = (unsigned short*)(base + 14 * MB);  // 4 MB bf16 (B,T,C)
  unsigned short* qtb   = (unsigned short*)(base + 18 * MB);  // 4 MB
  unsigned short* ktb   = (unsigned short*)(base + 22 * MB);  // 4 MB
  unsigned short* vtb   = (unsigned short*)(base + 30 * MB);  // 4 MB (B,C,T)
  unsigned short* obufb = (unsigned short*)(base + 34 * MB);  // 4 MB (B,T,C)
  float*          t1    = (float*)(base + 38 * MB);           // 8 MB fp32
  // t1b = t1 + MT*CQ (contiguous @46 MB, 8 MB) -- split-K partial 2
  unsigned short* hbuf  = qtb;   // FFN hidden bf16 (B,T,F): 16 MB over 18..34

  const unsigned short* wo  = wbuf + 786432;
  const unsigned short* wf1 = wbuf + 1048576;
  const unsigned short* wf2 = wbuf + 2097152;
  const long long sY = (long long)MT * CQ;
  float* t1b = t1 + sY;

  dim3 b256(256);
  dim3 gtr(TQ / 32, CQ / 32, BQ);
  dim3 gln(MT / 4);

  hipLaunchKernelGGL(tr_in, gtr, dim3(32, 8), 0, stream, x, xa, xab);

  for (int i = 0; i < LQ; i++) {
    hipLaunchKernelGGL(wconv, dim3(3072), b256, 0, stream,
        qw + (size_t)i * CQ * CQ, kw + (size_t)i * CQ * CQ,
        vw + (size_t)i * CQ * CQ, ow + (size_t)i * CQ * CQ,
        w1 + (size_t)i * FQ * CQ, w2 + (size_t)i * CQ * FQ, wbuf);
    // fused QKV: (4096 x 1536), V written transposed (B,C,T); 384 blocks
    hipLaunchKernelGGL(qkv_gemm, dim3(12, 32), b256, 0, stream,
        xab, wbuf, qtb, ktb, vtb, qbb + i * CQ, kbb + i * CQ, vbb + i * CQ);
    // attention: 64 Q rows/block, LDS-dbuf cooperative staging (512 blocks)
    hipLaunchKernelGGL(attn_kernel, dim3(TQ / 64, HQ, BQ), b256, 0, stream,
        qtb, ktb, vtb, mask, rk + (size_t)i * 576, rv + (size_t)i * 576, obufb);
    // o-proj split-K=2, 128x64 tiles -> 512 blocks, raw partials t1/t1b
    hipLaunchKernelGGL(mfma_gemm64, dim3(8, 32, 2), b256, 0, stream,
        obufb, wo, t1, MT, CQ, CQ / 2, CQ, CQ, (long long)(CQ / 2), sY);
    hipLaunchKernelGGL(ln_rows, gln, b256, 0, stream,
        xa, t1, t1b, obb + i * CQ, g1 + i * CQ, be1 + i * CQ, mask,
        xa, xab, 0);
    // FFN1 (512 blocks): premask+relu+postmask, bf16 out
    hipLaunchKernelGGL(mfma_gemm, dim3(16, 32, 1), b256, 0, stream,
        xab, wf1, (void*)hbuf, b1 + i * FQ, mask,
        MT, FQ, CQ, CQ, CQ, 0LL, 0LL, 1.f, 1 | 2 | 4 | 16);
    // FFN2 split-K=2, 128x64 tiles -> 512 blocks, raw partials
    hipLaunchKernelGGL(mfma_gemm64, dim3(8, 32, 2), b256, 0, stream,
        hbuf, wf2, t1, MT, CQ, FQ / 2, FQ, FQ, (long long)(FQ / 2), sY);
    hipLaunchKernelGGL(ln_rows, gln, b256, 0, stream,
        xa, t1, t1b, b2 + i * CQ, g2 + i * CQ, be2 + i * CQ, mask,
        xa, xab, 3);
  }
  hipLaunchKernelGGL(tr_out, gtr, dim3(32, 8), 0, stream, xa, out);
}

// Round 9
// 633.992 us; speedup vs baseline: 1.4292x; 1.0698x over previous
//
#include <hip/hip_runtime.h>

#define BQ 4
#define CQ 512
#define TQ 1024
#define FQ 2048
#define LQ 4
#define HQ 8
#define MT (BQ * TQ)            // batch-folded rows = 4096

typedef __attribute__((ext_vector_type(8))) short short8;
typedef __attribute__((ext_vector_type(4))) float floatx4;

#define MFMA16(a, b, c) __builtin_amdgcn_mfma_f32_16x16x32_bf16(a, b, c, 0, 0, 0)

static __device__ __forceinline__ unsigned short f2bf(float f) {
  union { float f; unsigned u; } v; v.f = f;
  unsigned r = v.u + 0x7fff + ((v.u >> 16) & 1);
  return (unsigned short)(r >> 16);
}

static __device__ __forceinline__ void async_copy16(const void* g, void* l) {
  __builtin_amdgcn_global_load_lds(
      (const __attribute__((address_space(1))) void*)g,
      (__attribute__((address_space(3))) void*)l, 16, 0, 0);
}

// ---------------------------------------------------------------------------
// bf16 MFMA GEMM, BK=64, XOR-swizzled LDS (slot = blk ^ (row&7)).
// Y[m,n] = epi( sum_k A[m, ko+k] B[n, ko+k] ), ko = z*kofs.
// 128x128 tile, 4 waves (2x2). flags: 1=relu 2=premask(row m)
// 4=postmask(row m) 16=bf16 out 32=raw fp32 (split-K partial, Y += z*sYb)
// Staging: per wave-call 64 chunks of 16B; lane L -> chunk cbase+L;
// LDS dest wave-uniform (HW lands lane at +L*16). Reads at slot q^(col&7)
// are conflict-free (8 distinct 16B blocks x stride coverage, 2-way max).
// ---------------------------------------------------------------------------
__global__ __launch_bounds__(256) void mfma_gemm(
    const unsigned short* __restrict__ A, const unsigned short* __restrict__ B,
    void* __restrict__ Y, const float* __restrict__ bias,
    const float* __restrict__ mask, int M, int N, int K, int lda, int ldb,
    long long kofs, long long sYb, float scale, int flags)
{
  const int tid = threadIdx.x;
  const int w = tid >> 6, lane = tid & 63;
  const int wm = w >> 1, wn = w & 1;
  const int m0 = blockIdx.y * 128, n0 = blockIdx.x * 128;
  const size_t ko = (size_t)blockIdx.z * kofs;

  __shared__ unsigned short sA[128 * 64];   // 16 KB
  __shared__ unsigned short sB[128 * 64];   // 16 KB

  floatx4 acc[4][4];
#pragma unroll
  for (int i = 0; i < 4; i++)
#pragma unroll
    for (int j = 0; j < 4; j++) acc[i][j] = floatx4{0.f, 0.f, 0.f, 0.f};

  const int col = lane & 15, gq = lane >> 4;
  const int xsw = col & 7;

  for (int k0 = 0; k0 < K; k0 += 64) {
    // stage 128 rows x 64k for A and B: 1024 chunks each, 4 rounds x 4 waves
#pragma unroll
    for (int r = 0; r < 4; r++) {
      const int cbase = w * 64 + r * 256;
      const int c = cbase + lane;
      const int row = c >> 3, p = c & 7;
      const int gb = (p ^ (row & 7)) * 8;
      async_copy16(&A[(size_t)(m0 + row) * lda + ko + k0 + gb], &sA[cbase * 8]);
      async_copy16(&B[(size_t)(n0 + row) * ldb + ko + k0 + gb], &sB[cbase * 8]);
    }
    __syncthreads();
#pragma unroll
    for (int kh = 0; kh < 2; kh++) {
      const int q = kh * 4 + gq;
      const int so = (q ^ xsw) * 8;
      short8 af[4], bfr[4];
#pragma unroll
      for (int im = 0; im < 4; im++)
        af[im] = *(const short8*)&sA[(wm * 64 + im * 16 + col) * 64 + so];
#pragma unroll
      for (int in = 0; in < 4; in++)
        bfr[in] = *(const short8*)&sB[(wn * 64 + in * 16 + col) * 64 + so];
#pragma unroll
      for (int im = 0; im < 4; im++)
#pragma unroll
        for (int in = 0; in < 4; in++)
          acc[im][in] = MFMA16(af[im], bfr[in], acc[im][in]);
    }
    __syncthreads();
  }

  const bool relu  = flags & 1;
  const bool prem  = flags & 2;
  const bool postm = flags & 4;
  const bool bf16o = flags & 16;
  const bool raw   = flags & 32;
  float* Yf = (float*)Y + (size_t)blockIdx.z * sYb;
  unsigned short* Yh = (unsigned short*)Y;

#pragma unroll
  for (int im = 0; im < 4; im++)
#pragma unroll
    for (int in = 0; in < 4; in++) {
      int nn = n0 + wn * 64 + in * 16 + col;
      float bn = raw ? 0.f : bias[nn];
#pragma unroll
      for (int reg = 0; reg < 4; reg++) {
        int mm = m0 + wm * 64 + im * 16 + gq * 4 + reg;
        float val = acc[im][in][reg];
        if (raw) {
          Yf[(size_t)mm * N + nn] = val;
        } else {
          float mv = (prem || postm) ? mask[mm] : 1.f;
          if (prem) val *= mv;
          val = (val + bn) * scale;
          if (relu) val = fmaxf(val, 0.f);
          if (postm) val *= mv;
          if (bf16o) Yh[(size_t)mm * N + nn] = f2bf(val);
          else       Yf[(size_t)mm * N + nn] = val;
        }
      }
    }
}

// ---------------------------------------------------------------------------
// 128m x 64n tile split-K GEMM, BK=64, swizzled; raw fp32 partials only.
// ---------------------------------------------------------------------------
__global__ __launch_bounds__(256) void mfma_gemm64(
    const unsigned short* __restrict__ A, const unsigned short* __restrict__ B,
    float* __restrict__ Y, int M, int N, int K, int lda, int ldb,
    long long kofs, long long sYb)
{
  const int tid = threadIdx.x;
  const int w = tid >> 6, lane = tid & 63;
  const int wm = w >> 1, wn = w & 1;
  const int m0 = blockIdx.y * 128, n0 = blockIdx.x * 64;
  const size_t ko = (size_t)blockIdx.z * kofs;

  __shared__ unsigned short sA[128 * 64];   // 16 KB
  __shared__ unsigned short sB[64 * 64];    // 8 KB

  floatx4 acc[4][2];
#pragma unroll
  for (int i = 0; i < 4; i++)
#pragma unroll
    for (int j = 0; j < 2; j++) acc[i][j] = floatx4{0.f, 0.f, 0.f, 0.f};

  const int col = lane & 15, gq = lane >> 4;
  const int xsw = col & 7;

  for (int k0 = 0; k0 < K; k0 += 64) {
#pragma unroll
    for (int r = 0; r < 4; r++) {
      const int cbase = w * 64 + r * 256;
      const int c = cbase + lane;
      const int row = c >> 3, p = c & 7;
      const int gb = (p ^ (row & 7)) * 8;
      async_copy16(&A[(size_t)(m0 + row) * lda + ko + k0 + gb], &sA[cbase * 8]);
    }
#pragma unroll
    for (int r = 0; r < 2; r++) {
      const int cbase = w * 64 + r * 256;
      const int c = cbase + lane;
      const int row = c >> 3, p = c & 7;
      const int gb = (p ^ (row & 7)) * 8;
      async_copy16(&B[(size_t)(n0 + row) * ldb + ko + k0 + gb], &sB[cbase * 8]);
    }
    __syncthreads();
#pragma unroll
    for (int kh = 0; kh < 2; kh++) {
      const int q = kh * 4 + gq;
      const int so = (q ^ xsw) * 8;
      short8 af[4], bfr[2];
#pragma unroll
      for (int im = 0; im < 4; im++)
        af[im] = *(const short8*)&sA[(wm * 64 + im * 16 + col) * 64 + so];
#pragma unroll
      for (int in = 0; in < 2; in++)
        bfr[in] = *(const short8*)&sB[(wn * 32 + in * 16 + col) * 64 + so];
#pragma unroll
      for (int im = 0; im < 4; im++)
#pragma unroll
        for (int in = 0; in < 2; in++)
          acc[im][in] = MFMA16(af[im], bfr[in], acc[im][in]);
    }
    __syncthreads();
  }

  float* Yf = Y + (size_t)blockIdx.z * sYb;
#pragma unroll
  for (int im = 0; im < 4; im++)
#pragma unroll
    for (int in = 0; in < 2; in++) {
      int nn = n0 + wn * 32 + in * 16 + col;
#pragma unroll
      for (int reg = 0; reg < 4; reg++) {
        int mm = m0 + wm * 64 + im * 16 + gq * 4 + reg;
        Yf[(size_t)mm * N + nn] = acc[im][in][reg];
      }
    }
}

// ---------------------------------------------------------------------------
// Fused QKV GEMM (BK=64, swizzled): A = x bf16 (MT x 512),
// B = [wq;wk;wv] bf16 (1536 x 512). Q scale 0.125.
// Q,K out bf16 (B,T,C); V out bf16 (B,C,T) (fused transpose).
// ---------------------------------------------------------------------------
__global__ __launch_bounds__(256) void qkv_gemm(
    const unsigned short* __restrict__ A, const unsigned short* __restrict__ B,
    unsigned short* __restrict__ qo, unsigned short* __restrict__ ko2,
    unsigned short* __restrict__ vo, const float* __restrict__ qb,
    const float* __restrict__ kb, const float* __restrict__ vb)
{
  const int tid = threadIdx.x;
  const int w = tid >> 6, lane = tid & 63;
  const int wm = w >> 1, wn = w & 1;
  const int m0 = blockIdx.y * 128, n0 = blockIdx.x * 128;

  __shared__ unsigned short sA[128 * 64];
  __shared__ unsigned short sB[128 * 64];

  floatx4 acc[4][4];
#pragma unroll
  for (int i = 0; i < 4; i++)
#pragma unroll
    for (int j = 0; j < 4; j++) acc[i][j] = floatx4{0.f, 0.f, 0.f, 0.f};

  const int col = lane & 15, gq = lane >> 4;
  const int xsw = col & 7;

  for (int k0 = 0; k0 < CQ; k0 += 64) {
#pragma unroll
    for (int r = 0; r < 4; r++) {
      const int cbase = w * 64 + r * 256;
      const int c = cbase + lane;
      const int row = c >> 3, p = c & 7;
      const int gb = (p ^ (row & 7)) * 8;
      async_copy16(&A[(size_t)(m0 + row) * CQ + k0 + gb], &sA[cbase * 8]);
      async_copy16(&B[(size_t)(n0 + row) * CQ + k0 + gb], &sB[cbase * 8]);
    }
    __syncthreads();
#pragma unroll
    for (int kh = 0; kh < 2; kh++) {
      const int q = kh * 4 + gq;
      const int so = (q ^ xsw) * 8;
      short8 af[4], bfr[4];
#pragma unroll
      for (int im = 0; im < 4; im++)
        af[im] = *(const short8*)&sA[(wm * 64 + im * 16 + col) * 64 + so];
#pragma unroll
      for (int in = 0; in < 4; in++)
        bfr[in] = *(const short8*)&sB[(wn * 64 + in * 16 + col) * 64 + so];
#pragma unroll
      for (int im = 0; im < 4; im++)
#pragma unroll
        for (int in = 0; in < 4; in++)
          acc[im][in] = MFMA16(af[im], bfr[in], acc[im][in]);
    }
    __syncthreads();
  }

  const int seg = n0 >> 9;
  const int nbase = n0 - seg * 512;

  if (seg < 2) {
    unsigned short* Yh = (seg == 0) ? qo : ko2;
    const float* bp = (seg == 0) ? qb : kb;
    const float scale = (seg == 0) ? 0.125f : 1.f;
#pragma unroll
    for (int im = 0; im < 4; im++)
#pragma unroll
      for (int in = 0; in < 4; in++) {
        int nn = nbase + wn * 64 + in * 16 + col;
        float bn = bp[nn];
#pragma unroll
        for (int reg = 0; reg < 4; reg++) {
          int mm = m0 + wm * 64 + im * 16 + gq * 4 + reg;
          Yh[(size_t)mm * CQ + nn] = f2bf((acc[im][in][reg] + bn) * scale);
        }
      }
  } else {
    // V: write (B,C,T) transposed; 4 consecutive t per lane -> ushort4
#pragma unroll
    for (int im = 0; im < 4; im++)
#pragma unroll
      for (int in = 0; in < 4; in++) {
        int nn = nbase + wn * 64 + in * 16 + col;
        float bn = vb[nn];
        int mm0 = m0 + wm * 64 + im * 16 + gq * 4;
        int bz = mm0 >> 10, t = mm0 & 1023;
        ushort4 uv = {f2bf(acc[im][in][0] + bn), f2bf(acc[im][in][1] + bn),
                      f2bf(acc[im][in][2] + bn), f2bf(acc[im][in][3] + bn)};
        *(ushort4*)&vo[((size_t)bz * CQ + nn) * TQ + t] = uv;
      }
  }
}

// ---------------------------------------------------------------------------
// MFMA flash attention (unchanged from round 8 — verified win).
// ---------------------------------------------------------------------------
__global__ __launch_bounds__(256) void attn_kernel(
    const unsigned short* __restrict__ qt, const unsigned short* __restrict__ kt,
    const unsigned short* __restrict__ vt, const float* __restrict__ mask,
    const float* __restrict__ rk, const float* __restrict__ rv,
    unsigned short* __restrict__ o)
{
  const int b = blockIdx.z, h = blockIdx.y;
  const int w = threadIdx.x >> 6;
  const int lane = threadIdx.x & 63;
  const int col = lane & 15, g = lane >> 4;
  const int i0 = blockIdx.x * 64 + w * 16;

  const unsigned short* qb = qt + (size_t)b * TQ * CQ + h * 64;
  const unsigned short* kb = kt + (size_t)b * TQ * CQ + h * 64;
  const unsigned short* vb = vt + ((size_t)b * CQ + h * 64) * TQ;
  unsigned short* ob = o + (size_t)b * TQ * CQ + h * 64;

  __shared__ unsigned short sK[2][64 * 64];
  __shared__ unsigned short sV[2][64 * 64];
  __shared__ unsigned short pbuf[4][16][72];
  __shared__ float rkdl[4][16][9];
  __shared__ float pband[4][16][9];
  __shared__ float smask[TQ];

  short8 qf0 = *(const short8*)&qb[(size_t)(i0 + col) * CQ + g * 8];
  short8 qf1 = *(const short8*)&qb[(size_t)(i0 + col) * CQ + 32 + g * 8];

  {
    short8 rb0 = {0, 0, 0, 0, 0, 0, 0, 0}, rb1 = rb0;
    if (col < 9) {
#pragma unroll
      for (int i = 0; i < 8; i++) {
        rb0[i] = (short)f2bf(rk[col * 64 + g * 8 + i]);
        rb1[i] = (short)f2bf(rk[col * 64 + 32 + g * 8 + i]);
      }
    }
    floatx4 rc = {0.f, 0.f, 0.f, 0.f};
    rc = MFMA16(qf0, rb0, rc);
    rc = MFMA16(qf1, rb1, rc);
    if (col < 9) {
#pragma unroll
      for (int reg = 0; reg < 4; reg++) rkdl[w][g * 4 + reg][col] = rc[reg];
    }
  }
  for (int e = lane; e < 144; e += 64) pband[w][e / 9][e % 9] = 0.f;
  {
    float4 mvv = *(const float4*)&mask[(size_t)b * TQ + threadIdx.x * 4];
    *(float4*)&smask[threadIdx.x * 4] = mvv;
  }

  const int prow = lane >> 3;
  const int pblk = (lane & 7) ^ prow;
  const int eblk0 = ((0 * 4 + g) ^ (col & 7)) * 8;
  const int eblk1 = ((1 * 4 + g) ^ (col & 7)) * 8;

#pragma unroll
  for (int q = 0; q < 2; q++) {
    int s = w * 2 + q;
    async_copy16(&kb[(size_t)(s * 8 + prow) * CQ + pblk * 8], &sK[0][s * 512]);
    async_copy16(&vb[(size_t)(s * 8 + prow) * TQ + 0 + pblk * 8], &sV[0][s * 512]);
  }

  float l_lane[4] = {0.f, 0.f, 0.f, 0.f};
  floatx4 oacc[4];
#pragma unroll
  for (int r = 0; r < 4; r++) oacc[r] = floatx4{0.f, 0.f, 0.f, 0.f};

  for (int jt = 0; jt < 16; jt++) {
    const int cur = jt & 1, nx = cur ^ 1;
    __syncthreads();
    if (jt < 15) {
      const int j0n = (jt + 1) * 64;
#pragma unroll
      for (int q = 0; q < 2; q++) {
        int s = w * 2 + q;
        async_copy16(&kb[(size_t)(j0n + s * 8 + prow) * CQ + pblk * 8],
                     &sK[nx][s * 512]);
        async_copy16(&vb[(size_t)(s * 8 + prow) * TQ + j0n + pblk * 8],
                     &sV[nx][s * 512]);
      }
    }
    const int j0 = jt * 64;

    floatx4 sc[4];
#pragma unroll
    for (int jg = 0; jg < 4; jg++) {
      const int r = (jg * 16 + col) * 64;
      short8 kf0 = *(const short8*)&sK[cur][r + eblk0];
      short8 kf1 = *(const short8*)&sK[cur][r + eblk1];
      floatx4 z = {0.f, 0.f, 0.f, 0.f};
      z = MFMA16(qf0, kf0, z);
      sc[jg] = MFMA16(qf1, kf1, z);
    }

    const bool inband = (j0 <= i0 + 19) && (j0 + 63 >= i0 - 4);

    float p[4][4];
#pragma unroll
    for (int reg = 0; reg < 4; reg++) {
      const int ig = i0 + g * 4 + reg;
#pragma unroll
      for (int jg = 0; jg < 4; jg++) {
        float s = sc[jg][reg];
        if (inband) {
          int dlt = j0 + jg * 16 + col - ig + 4;
          if (dlt >= 0 && dlt < 9) s += rkdl[w][g * 4 + reg][dlt];
        }
        float pv = (smask[j0 + jg * 16 + col] == 0.f) ? 0.f : __expf(s);
        p[reg][jg] = pv;
        l_lane[reg] += pv;
      }
    }

    if (inband) {
#pragma unroll
      for (int reg = 0; reg < 4; reg++) {
        const int row = g * 4 + reg;
#pragma unroll
        for (int jg = 0; jg < 4; jg++) {
          int dlt = j0 + jg * 16 + col - (i0 + row) + 4;
          if (dlt >= 0 && dlt < 9) pband[w][row][dlt] = p[reg][jg];
        }
      }
    }

#pragma unroll
    for (int reg = 0; reg < 4; reg++)
#pragma unroll
      for (int jg = 0; jg < 4; jg++)
        pbuf[w][g * 4 + reg][jg * 16 + col] = f2bf(p[reg][jg]);
    __builtin_amdgcn_wave_barrier();
    short8 pf0 = *(const short8*)&pbuf[w][col][g * 8];
    short8 pf1 = *(const short8*)&pbuf[w][col][32 + g * 8];

#pragma unroll
    for (int dg = 0; dg < 4; dg++) {
      const int r = (dg * 16 + col) * 64;
      short8 vf0 = *(const short8*)&sV[cur][r + eblk0];
      short8 vf1 = *(const short8*)&sV[cur][r + eblk1];
      oacc[dg] = MFMA16(pf0, vf0, oacc[dg]);
      oacc[dg] = MFMA16(pf1, vf1, oacc[dg]);
    }
    __builtin_amdgcn_wave_barrier();
  }

  float inv_l[4];
#pragma unroll
  for (int reg = 0; reg < 4; reg++) {
    float l = l_lane[reg];
#pragma unroll
    for (int off = 1; off < 16; off <<= 1) l += __shfl_xor(l, off, 64);
    inv_l[reg] = 1.f / l;
  }

#pragma unroll
  for (int dg = 0; dg < 4; dg++) {
    float rvc[4] = {0.f, 0.f, 0.f, 0.f};
#pragma unroll
    for (int dlt = 0; dlt < 9; dlt++) {
      float rvv = rv[dlt * 64 + dg * 16 + col];
#pragma unroll
      for (int reg = 0; reg < 4; reg++)
        rvc[reg] += pband[w][g * 4 + reg][dlt] * rvv;
    }
#pragma unroll
    for (int reg = 0; reg < 4; reg++) {
      float val = (oacc[dg][reg] + rvc[reg]) * inv_l[reg];
      ob[(size_t)(i0 + g * 4 + reg) * CQ + dg * 16 + col] = f2bf(val);
    }
  }
}

// ---------------------------------------------------------------------------
// Residual + LayerNorm rows (C=512 contiguous). v = res + s*(a1+a2+addb[c]),
// s = mask if (mode&1). y = LN(v)*g+b; if (mode&2) y *= mask.
// ---------------------------------------------------------------------------
__global__ __launch_bounds__(256) void ln_rows(
    const float* __restrict__ res, const float* __restrict__ a1,
    const float* __restrict__ a2, const float* __restrict__ addb,
    const float* __restrict__ g, const float* __restrict__ bb,
    const float* __restrict__ mask, float* __restrict__ outf,
    unsigned short* __restrict__ outb, int mode)
{
  const int row = blockIdx.x * 4 + (threadIdx.x >> 6);
  const int lane = threadIdx.x & 63;
  const size_t base = (size_t)row * CQ + lane * 8;
  const int c0 = lane * 8;

  float mv = mask[row];
  float sadd = (mode & 1) ? mv : 1.f;

  float v[8];
#pragma unroll
  for (int i = 0; i < 8; i += 4) {
    float4 r = *(const float4*)&res[base + i];
    float4 x1 = *(const float4*)&a1[base + i];
    float4 x2 = *(const float4*)&a2[base + i];
    float4 bv = *(const float4*)&addb[c0 + i];
    v[i + 0] = r.x + sadd * (x1.x + x2.x + bv.x);
    v[i + 1] = r.y + sadd * (x1.y + x2.y + bv.y);
    v[i + 2] = r.z + sadd * (x1.z + x2.z + bv.z);
    v[i + 3] = r.w + sadd * (x1.w + x2.w + bv.w);
  }
  float sum = 0.f, ssq = 0.f;
#pragma unroll
  for (int i = 0; i < 8; i++) { sum += v[i]; ssq += v[i] * v[i]; }
#pragma unroll
  for (int off = 1; off < 64; off <<= 1) {
    sum += __shfl_xor(sum, off, 64);
    ssq += __shfl_xor(ssq, off, 64);
  }
  float mean = sum * (1.f / CQ);
  float var = ssq * (1.f / CQ) - mean * mean;
  float rstd = rsqrtf(var + 1e-6f);
  float pm = (mode & 2) ? mv : 1.f;

  float y[8];
#pragma unroll
  for (int i = 0; i < 8; i++)
    y[i] = ((v[i] - mean) * rstd * g[c0 + i] + bb[c0 + i]) * pm;
  float4 o0 = {y[0], y[1], y[2], y[3]}, o1 = {y[4], y[5], y[6], y[7]};
  *(float4*)&outf[base] = o0;
  *(float4*)&outf[base + 4] = o1;
  if (outb) {
    ushort4 u0 = {f2bf(y[0]), f2bf(y[1]), f2bf(y[2]), f2bf(y[3])};
    ushort4 u1 = {f2bf(y[4]), f2bf(y[5]), f2bf(y[6]), f2bf(y[7])};
    *(ushort4*)&outb[base] = u0;
    *(ushort4*)&outb[base + 4] = u1;
  }
}

// ---------------------------------------------------------------------------
// Transpose-in: x (B,C,T) fp32 -> xa fp32 (B,T,C) + xab bf16 (B,T,C)
// ---------------------------------------------------------------------------
__global__ __launch_bounds__(256) void tr_in(
    const float* __restrict__ x, float* __restrict__ xa,
    unsigned short* __restrict__ xab)
{
  __shared__ float s[32][33];
  const int b = blockIdx.z, t0 = blockIdx.x * 32, c0 = blockIdx.y * 32;
  const int tx = threadIdx.x, ty = threadIdx.y;
#pragma unroll
  for (int r = 0; r < 4; r++)
    s[ty + r * 8][tx] = x[((size_t)b * CQ + c0 + ty + r * 8) * TQ + t0 + tx];
  __syncthreads();
#pragma unroll
  for (int r = 0; r < 4; r++) {
    float v = s[tx][ty + r * 8];
    size_t idx = ((size_t)b * TQ + t0 + ty + r * 8) * CQ + c0 + tx;
    xa[idx] = v;
    xab[idx] = f2bf(v);
  }
}

// ---------------------------------------------------------------------------
// Transpose-out: y (B,T,C) fp32 -> out (B,C,T) fp32
// ---------------------------------------------------------------------------
__global__ __launch_bounds__(256) void tr_out(
    const float* __restrict__ y, float* __restrict__ out)
{
  __shared__ float s[32][33];
  const int b = blockIdx.z, t0 = blockIdx.x * 32, c0 = blockIdx.y * 32;
  const int tx = threadIdx.x, ty = threadIdx.y;
#pragma unroll
  for (int r = 0; r < 4; r++)
    s[ty + r * 8][tx] = y[((size_t)b * TQ + t0 + ty + r * 8) * CQ + c0 + tx];
  __syncthreads();
#pragma unroll
  for (int r = 0; r < 4; r++)
    out[((size_t)b * CQ + c0 + ty + r * 8) * TQ + t0 + tx] = s[tx][ty + r * 8];
}

// ---------------------------------------------------------------------------
// ALL-layer weight fp32 -> bf16, one launch. Per-layer block (3,145,728 el):
// [qkv 786432][ow 262144][w1 1048576][w2 1048576]
// ---------------------------------------------------------------------------
__global__ __launch_bounds__(256) void wconv_all(
    const float* __restrict__ qw, const float* __restrict__ kw,
    const float* __restrict__ vw, const float* __restrict__ ow,
    const float* __restrict__ w1, const float* __restrict__ w2,
    unsigned short* __restrict__ dst)
{
  const int PER_L4 = 786432;                   // float4 groups per layer
  int idx4 = blockIdx.x * 256 + threadIdx.x;   // 3,145,728 total
  int l = idx4 / PER_L4;
  int e = (idx4 - l * PER_L4) * 4;             // elem within layer block
  const float* src;
  size_t off;
  if (e < 786432) {
    int which = e >> 18;
    src = (which == 0) ? qw : (which == 1) ? kw : vw;
    off = (size_t)l * 262144 + (e & 262143);
  } else if (e < 1048576) {
    src = ow;  off = (size_t)l * 262144 + (e - 786432);
  } else if (e < 2097152) {
    src = w1;  off = (size_t)l * 1048576 + (e - 1048576);
  } else {
    src = w2;  off = (size_t)l * 1048576 + (e - 2097152);
  }
  float4 v = *(const float4*)&src[off];
  ushort4 u = {f2bf(v.x), f2bf(v.y), f2bf(v.z), f2bf(v.w)};
  *(ushort4*)&dst[(size_t)l * 3145728 + e] = u;
}

// ---------------------------------------------------------------------------
extern "C" void kernel_launch(void* const* d_in, const int* in_sizes, int n_in,
                              void* d_out, int out_size, void* d_ws, size_t ws_size,
                              hipStream_t stream) {
  const float* x    = (const float*)d_in[0];
  const float* mask = (const float*)d_in[1];
  const float* qw   = (const float*)d_in[2];
  const float* qbb  = (const float*)d_in[3];
  const float* kw   = (const float*)d_in[4];
  const float* kbb  = (const float*)d_in[5];
  const float* vw   = (const float*)d_in[6];
  const float* vbb  = (const float*)d_in[7];
  const float* ow   = (const float*)d_in[8];
  const float* obb  = (const float*)d_in[9];
  const float* rk   = (const float*)d_in[10];
  const float* rv   = (const float*)d_in[11];
  const float* g1   = (const float*)d_in[12];
  const float* be1  = (const float*)d_in[13];
  const float* w1   = (const float*)d_in[14];
  const float* b1   = (const float*)d_in[15];
  const float* w2   = (const float*)d_in[16];
  const float* b2   = (const float*)d_in[17];
  const float* g2   = (const float*)d_in[18];
  const float* be2  = (const float*)d_in[19];
  float* out = (float*)d_out;

  const size_t MB = 1 << 20;
  char* base = (char*)d_ws;
  unsigned short* wbufA = (unsigned short*)(base);            // 24 MB (all layers)
  float*          xa    = (float*)(base + 24 * MB);           // 8 MB fp32 (B,T,C)
  unsigned short* xab   = (unsigned short*)(base + 32 * MB);  // 4 MB bf16 (B,T,C)
  unsigned short* qtb   = (unsigned short*)(base + 36 * MB);  // 4 MB
  unsigned short* ktb   = (unsigned short*)(base + 40 * MB);  // 4 MB
  unsigned short* vtb   = (unsigned short*)(base + 44 * MB);  // 4 MB (B,C,T)
  unsigned short* obufb = (unsigned short*)(base + 48 * MB);  // 4 MB (B,T,C)
  float*          t1    = (float*)(base + 52 * MB);           // 8 MB fp32
  // t1b = t1 + MT*CQ (@60 MB, 8 MB) -- split-K partial 2
  unsigned short* hbuf  = qtb;   // FFN hidden bf16 (B,T,F): 16 MB over 36..52

  const long long sY = (long long)MT * CQ;
  float* t1b = t1 + sY;

  dim3 b256(256);
  dim3 gtr(TQ / 32, CQ / 32, BQ);
  dim3 gln(MT / 4);

  hipLaunchKernelGGL(tr_in, gtr, dim3(32, 8), 0, stream, x, xa, xab);
  hipLaunchKernelGGL(wconv_all, dim3(12288), b256, 0, stream,
      qw, kw, vw, ow, w1, w2, wbufA);

  for (int i = 0; i < LQ; i++) {
    const unsigned short* wl  = wbufA + (size_t)i * 3145728;
    const unsigned short* wo  = wl + 786432;
    const unsigned short* wf1 = wl + 1048576;
    const unsigned short* wf2 = wl + 2097152;
    // fused QKV: (4096 x 1536), V written transposed (B,C,T); 384 blocks
    hipLaunchKernelGGL(qkv_gemm, dim3(12, 32), b256, 0, stream,
        xab, wl, qtb, ktb, vtb, qbb + i * CQ, kbb + i * CQ, vbb + i * CQ);
    // attention: 64 Q rows/block, LDS-dbuf cooperative staging (512 blocks)
    hipLaunchKernelGGL(attn_kernel, dim3(TQ / 64, HQ, BQ), b256, 0, stream,
        qtb, ktb, vtb, mask, rk + (size_t)i * 576, rv + (size_t)i * 576, obufb);
    // o-proj split-K=2, 128x64 tiles -> 512 blocks, raw partials t1/t1b
    hipLaunchKernelGGL(mfma_gemm64, dim3(8, 32, 2), b256, 0, stream,
        obufb, wo, t1, MT, CQ, CQ / 2, CQ, CQ, (long long)(CQ / 2), sY);
    hipLaunchKernelGGL(ln_rows, gln, b256, 0, stream,
        xa, t1, t1b, obb + i * CQ, g1 + i * CQ, be1 + i * CQ, mask,
        xa, xab, 0);
    // FFN1 (512 blocks): premask+relu+postmask, bf16 out
    hipLaunchKernelGGL(mfma_gemm, dim3(16, 32, 1), b256, 0, stream,
        xab, wf1, (void*)hbuf, b1 + i * FQ, mask,
        MT, FQ, CQ, CQ, CQ, 0LL, 0LL, 1.f, 1 | 2 | 4 | 16);
    // FFN2 split-K=2, 128x64 tiles -> 512 blocks, raw partials
    hipLaunchKernelGGL(mfma_gemm64, dim3(8, 32, 2), b256, 0, stream,
        hbuf, wf2, t1, MT, CQ, FQ / 2, FQ, FQ, (long long)(FQ / 2), sY);
    hipLaunchKernelGGL(ln_rows, gln, b256, 0, stream,
        xa, t1, t1b, b2 + i * CQ, g2 + i * CQ, be2 + i * CQ, mask,
        xa, xab, 3);
  }
  hipLaunchKernelGGL(tr_out, gtr, dim3(32, 8), 0, stream, xa, out);
}

// Round 10
// 626.335 us; speedup vs baseline: 1.4466x; 1.0122x over previous
//
#include <hip/hip_runtime.h>

#define BQ 4
#define CQ 512
#define TQ 1024
#define FQ 2048
#define LQ 4
#define HQ 8
#define MT (BQ * TQ)            // batch-folded rows = 4096

typedef __attribute__((ext_vector_type(8))) short short8;
typedef __attribute__((ext_vector_type(4))) float floatx4;

#define MFMA16(a, b, c) __builtin_amdgcn_mfma_f32_16x16x32_bf16(a, b, c, 0, 0, 0)

static __device__ __forceinline__ unsigned short f2bf(float f) {
  union { float f; unsigned u; } v; v.f = f;
  unsigned r = v.u + 0x7fff + ((v.u >> 16) & 1);
  return (unsigned short)(r >> 16);
}

static __device__ __forceinline__ void async_copy16(const void* g, void* l) {
  __builtin_amdgcn_global_load_lds(
      (const __attribute__((address_space(1))) void*)g,
      (__attribute__((address_space(3))) void*)l, 16, 0, 0);
}

// ---------------------------------------------------------------------------
// bf16 MFMA GEMM, BK=64, XOR-swizzled LDS, DOUBLE-BUFFERED staging.
// Y[m,n] = epi( sum_k A[m, ko+k] B[n, ko+k] ), ko = z*kofs.
// 128x128 tile, 4 waves (2x2). flags: 1=relu 2=premask(row m)
// 4=postmask(row m) 16=bf16 out 32=raw fp32 (split-K partial, Y += z*sYb)
// ---------------------------------------------------------------------------
__global__ __launch_bounds__(256) void mfma_gemm(
    const unsigned short* __restrict__ A, const unsigned short* __restrict__ B,
    void* __restrict__ Y, const float* __restrict__ bias,
    const float* __restrict__ mask, int M, int N, int K, int lda, int ldb,
    long long kofs, long long sYb, float scale, int flags)
{
  const int tid = threadIdx.x;
  const int w = tid >> 6, lane = tid & 63;
  const int wm = w >> 1, wn = w & 1;
  const int m0 = blockIdx.y * 128, n0 = blockIdx.x * 128;
  const size_t ko = (size_t)blockIdx.z * kofs;

  __shared__ unsigned short sA[2][128 * 64];   // 16 KB x2
  __shared__ unsigned short sB[2][128 * 64];   // 16 KB x2

  floatx4 acc[4][4];
#pragma unroll
  for (int i = 0; i < 4; i++)
#pragma unroll
    for (int j = 0; j < 4; j++) acc[i][j] = floatx4{0.f, 0.f, 0.f, 0.f};

  const int col = lane & 15, gq = lane >> 4;
  const int xsw = col & 7;

  auto stage = [&](int buf, int k0) {
#pragma unroll
    for (int r = 0; r < 4; r++) {
      const int cbase = w * 64 + r * 256;
      const int c = cbase + lane;
      const int row = c >> 3, p = c & 7;
      const int gb = (p ^ (row & 7)) * 8;
      async_copy16(&A[(size_t)(m0 + row) * lda + ko + k0 + gb],
                   &sA[buf][cbase * 8]);
      async_copy16(&B[(size_t)(n0 + row) * ldb + ko + k0 + gb],
                   &sB[buf][cbase * 8]);
    }
  };

  stage(0, 0);
  const int nit = K >> 6;
  for (int it = 0; it < nit; it++) {
    const int cur = it & 1;
    __syncthreads();  // buf[cur] staged; prior compute on buf[cur^1] done
    if (it + 1 < nit) stage(cur ^ 1, (it + 1) << 6);
#pragma unroll
    for (int kh = 0; kh < 2; kh++) {
      const int q = kh * 4 + gq;
      const int so = (q ^ xsw) * 8;
      short8 af[4], bfr[4];
#pragma unroll
      for (int im = 0; im < 4; im++)
        af[im] = *(const short8*)&sA[cur][(wm * 64 + im * 16 + col) * 64 + so];
#pragma unroll
      for (int in = 0; in < 4; in++)
        bfr[in] = *(const short8*)&sB[cur][(wn * 64 + in * 16 + col) * 64 + so];
#pragma unroll
      for (int im = 0; im < 4; im++)
#pragma unroll
        for (int in = 0; in < 4; in++)
          acc[im][in] = MFMA16(af[im], bfr[in], acc[im][in]);
    }
  }

  const bool relu  = flags & 1;
  const bool prem  = flags & 2;
  const bool postm = flags & 4;
  const bool bf16o = flags & 16;
  const bool raw   = flags & 32;
  float* Yf = (float*)Y + (size_t)blockIdx.z * sYb;
  unsigned short* Yh = (unsigned short*)Y;

#pragma unroll
  for (int im = 0; im < 4; im++)
#pragma unroll
    for (int in = 0; in < 4; in++) {
      int nn = n0 + wn * 64 + in * 16 + col;
      float bn = raw ? 0.f : bias[nn];
#pragma unroll
      for (int reg = 0; reg < 4; reg++) {
        int mm = m0 + wm * 64 + im * 16 + gq * 4 + reg;
        float val = acc[im][in][reg];
        if (raw) {
          Yf[(size_t)mm * N + nn] = val;
        } else {
          float mv = (prem || postm) ? mask[mm] : 1.f;
          if (prem) val *= mv;
          val = (val + bn) * scale;
          if (relu) val = fmaxf(val, 0.f);
          if (postm) val *= mv;
          if (bf16o) Yh[(size_t)mm * N + nn] = f2bf(val);
          else       Yf[(size_t)mm * N + nn] = val;
        }
      }
    }
}

// ---------------------------------------------------------------------------
// 128m x 64n tile split-K GEMM, BK=64, swizzled, double-buffered; raw fp32.
// ---------------------------------------------------------------------------
__global__ __launch_bounds__(256) void mfma_gemm64(
    const unsigned short* __restrict__ A, const unsigned short* __restrict__ B,
    float* __restrict__ Y, int M, int N, int K, int lda, int ldb,
    long long kofs, long long sYb)
{
  const int tid = threadIdx.x;
  const int w = tid >> 6, lane = tid & 63;
  const int wm = w >> 1, wn = w & 1;
  const int m0 = blockIdx.y * 128, n0 = blockIdx.x * 64;
  const size_t ko = (size_t)blockIdx.z * kofs;

  __shared__ unsigned short sA[2][128 * 64];   // 16 KB x2
  __shared__ unsigned short sB[2][64 * 64];    // 8 KB x2

  floatx4 acc[4][2];
#pragma unroll
  for (int i = 0; i < 4; i++)
#pragma unroll
    for (int j = 0; j < 2; j++) acc[i][j] = floatx4{0.f, 0.f, 0.f, 0.f};

  const int col = lane & 15, gq = lane >> 4;
  const int xsw = col & 7;

  auto stage = [&](int buf, int k0) {
#pragma unroll
    for (int r = 0; r < 4; r++) {
      const int cbase = w * 64 + r * 256;
      const int c = cbase + lane;
      const int row = c >> 3, p = c & 7;
      const int gb = (p ^ (row & 7)) * 8;
      async_copy16(&A[(size_t)(m0 + row) * lda + ko + k0 + gb],
                   &sA[buf][cbase * 8]);
    }
#pragma unroll
    for (int r = 0; r < 2; r++) {
      const int cbase = w * 64 + r * 256;
      const int c = cbase + lane;
      const int row = c >> 3, p = c & 7;
      const int gb = (p ^ (row & 7)) * 8;
      async_copy16(&B[(size_t)(n0 + row) * ldb + ko + k0 + gb],
                   &sB[buf][cbase * 8]);
    }
  };

  stage(0, 0);
  const int nit = K >> 6;
  for (int it = 0; it < nit; it++) {
    const int cur = it & 1;
    __syncthreads();
    if (it + 1 < nit) stage(cur ^ 1, (it + 1) << 6);
#pragma unroll
    for (int kh = 0; kh < 2; kh++) {
      const int q = kh * 4 + gq;
      const int so = (q ^ xsw) * 8;
      short8 af[4], bfr[2];
#pragma unroll
      for (int im = 0; im < 4; im++)
        af[im] = *(const short8*)&sA[cur][(wm * 64 + im * 16 + col) * 64 + so];
#pragma unroll
      for (int in = 0; in < 2; in++)
        bfr[in] = *(const short8*)&sB[cur][(wn * 32 + in * 16 + col) * 64 + so];
#pragma unroll
      for (int im = 0; im < 4; im++)
#pragma unroll
        for (int in = 0; in < 2; in++)
          acc[im][in] = MFMA16(af[im], bfr[in], acc[im][in]);
    }
  }

  float* Yf = Y + (size_t)blockIdx.z * sYb;
#pragma unroll
  for (int im = 0; im < 4; im++)
#pragma unroll
    for (int in = 0; in < 2; in++) {
      int nn = n0 + wn * 32 + in * 16 + col;
#pragma unroll
      for (int reg = 0; reg < 4; reg++) {
        int mm = m0 + wm * 64 + im * 16 + gq * 4 + reg;
        Yf[(size_t)mm * N + nn] = acc[im][in][reg];
      }
    }
}

// ---------------------------------------------------------------------------
// Fused QKV GEMM (BK=64, swizzled, double-buffered): A = x bf16 (MT x 512),
// B = [wq;wk;wv] bf16 (1536 x 512). Q scale 0.125.
// Q,K out bf16 (B,T,C); V out bf16 (B,C,T) (fused transpose).
// ---------------------------------------------------------------------------
__global__ __launch_bounds__(256) void qkv_gemm(
    const unsigned short* __restrict__ A, const unsigned short* __restrict__ B,
    unsigned short* __restrict__ qo, unsigned short* __restrict__ ko2,
    unsigned short* __restrict__ vo, const float* __restrict__ qb,
    const float* __restrict__ kb, const float* __restrict__ vb)
{
  const int tid = threadIdx.x;
  const int w = tid >> 6, lane = tid & 63;
  const int wm = w >> 1, wn = w & 1;
  const int m0 = blockIdx.y * 128, n0 = blockIdx.x * 128;

  __shared__ unsigned short sA[2][128 * 64];
  __shared__ unsigned short sB[2][128 * 64];

  floatx4 acc[4][4];
#pragma unroll
  for (int i = 0; i < 4; i++)
#pragma unroll
    for (int j = 0; j < 4; j++) acc[i][j] = floatx4{0.f, 0.f, 0.f, 0.f};

  const int col = lane & 15, gq = lane >> 4;
  const int xsw = col & 7;

  auto stage = [&](int buf, int k0) {
#pragma unroll
    for (int r = 0; r < 4; r++) {
      const int cbase = w * 64 + r * 256;
      const int c = cbase + lane;
      const int row = c >> 3, p = c & 7;
      const int gb = (p ^ (row & 7)) * 8;
      async_copy16(&A[(size_t)(m0 + row) * CQ + k0 + gb], &sA[buf][cbase * 8]);
      async_copy16(&B[(size_t)(n0 + row) * CQ + k0 + gb], &sB[buf][cbase * 8]);
    }
  };

  stage(0, 0);
  const int nit = CQ >> 6;
  for (int it = 0; it < nit; it++) {
    const int cur = it & 1;
    __syncthreads();
    if (it + 1 < nit) stage(cur ^ 1, (it + 1) << 6);
#pragma unroll
    for (int kh = 0; kh < 2; kh++) {
      const int q = kh * 4 + gq;
      const int so = (q ^ xsw) * 8;
      short8 af[4], bfr[4];
#pragma unroll
      for (int im = 0; im < 4; im++)
        af[im] = *(const short8*)&sA[cur][(wm * 64 + im * 16 + col) * 64 + so];
#pragma unroll
      for (int in = 0; in < 4; in++)
        bfr[in] = *(const short8*)&sB[cur][(wn * 64 + in * 16 + col) * 64 + so];
#pragma unroll
      for (int im = 0; im < 4; im++)
#pragma unroll
        for (int in = 0; in < 4; in++)
          acc[im][in] = MFMA16(af[im], bfr[in], acc[im][in]);
    }
  }

  const int seg = n0 >> 9;
  const int nbase = n0 - seg * 512;

  if (seg < 2) {
    unsigned short* Yh = (seg == 0) ? qo : ko2;
    const float* bp = (seg == 0) ? qb : kb;
    const float scale = (seg == 0) ? 0.125f : 1.f;
#pragma unroll
    for (int im = 0; im < 4; im++)
#pragma unroll
      for (int in = 0; in < 4; in++) {
        int nn = nbase + wn * 64 + in * 16 + col;
        float bn = bp[nn];
#pragma unroll
        for (int reg = 0; reg < 4; reg++) {
          int mm = m0 + wm * 64 + im * 16 + gq * 4 + reg;
          Yh[(size_t)mm * CQ + nn] = f2bf((acc[im][in][reg] + bn) * scale);
        }
      }
  } else {
    // V: write (B,C,T) transposed; 4 consecutive t per lane -> ushort4
#pragma unroll
    for (int im = 0; im < 4; im++)
#pragma unroll
      for (int in = 0; in < 4; in++) {
        int nn = nbase + wn * 64 + in * 16 + col;
        float bn = vb[nn];
        int mm0 = m0 + wm * 64 + im * 16 + gq * 4;
        int bz = mm0 >> 10, t = mm0 & 1023;
        ushort4 uv = {f2bf(acc[im][in][0] + bn), f2bf(acc[im][in][1] + bn),
                      f2bf(acc[im][in][2] + bn), f2bf(acc[im][in][3] + bn)};
        *(ushort4*)&vo[((size_t)bz * CQ + nn) * TQ + t] = uv;
      }
  }
}

// ---------------------------------------------------------------------------
// MFMA flash attention (unchanged from round 8 — verified win).
// ---------------------------------------------------------------------------
__global__ __launch_bounds__(256) void attn_kernel(
    const unsigned short* __restrict__ qt, const unsigned short* __restrict__ kt,
    const unsigned short* __restrict__ vt, const float* __restrict__ mask,
    const float* __restrict__ rk, const float* __restrict__ rv,
    unsigned short* __restrict__ o)
{
  const int b = blockIdx.z, h = blockIdx.y;
  const int w = threadIdx.x >> 6;
  const int lane = threadIdx.x & 63;
  const int col = lane & 15, g = lane >> 4;
  const int i0 = blockIdx.x * 64 + w * 16;

  const unsigned short* qb = qt + (size_t)b * TQ * CQ + h * 64;
  const unsigned short* kb = kt + (size_t)b * TQ * CQ + h * 64;
  const unsigned short* vb = vt + ((size_t)b * CQ + h * 64) * TQ;
  unsigned short* ob = o + (size_t)b * TQ * CQ + h * 64;

  __shared__ unsigned short sK[2][64 * 64];
  __shared__ unsigned short sV[2][64 * 64];
  __shared__ unsigned short pbuf[4][16][72];
  __shared__ float rkdl[4][16][9];
  __shared__ float pband[4][16][9];
  __shared__ float smask[TQ];

  short8 qf0 = *(const short8*)&qb[(size_t)(i0 + col) * CQ + g * 8];
  short8 qf1 = *(const short8*)&qb[(size_t)(i0 + col) * CQ + 32 + g * 8];

  {
    short8 rb0 = {0, 0, 0, 0, 0, 0, 0, 0}, rb1 = rb0;
    if (col < 9) {
#pragma unroll
      for (int i = 0; i < 8; i++) {
        rb0[i] = (short)f2bf(rk[col * 64 + g * 8 + i]);
        rb1[i] = (short)f2bf(rk[col * 64 + 32 + g * 8 + i]);
      }
    }
    floatx4 rc = {0.f, 0.f, 0.f, 0.f};
    rc = MFMA16(qf0, rb0, rc);
    rc = MFMA16(qf1, rb1, rc);
    if (col < 9) {
#pragma unroll
      for (int reg = 0; reg < 4; reg++) rkdl[w][g * 4 + reg][col] = rc[reg];
    }
  }
  for (int e = lane; e < 144; e += 64) pband[w][e / 9][e % 9] = 0.f;
  {
    float4 mvv = *(const float4*)&mask[(size_t)b * TQ + threadIdx.x * 4];
    *(float4*)&smask[threadIdx.x * 4] = mvv;
  }

  const int prow = lane >> 3;
  const int pblk = (lane & 7) ^ prow;
  const int eblk0 = ((0 * 4 + g) ^ (col & 7)) * 8;
  const int eblk1 = ((1 * 4 + g) ^ (col & 7)) * 8;

#pragma unroll
  for (int q = 0; q < 2; q++) {
    int s = w * 2 + q;
    async_copy16(&kb[(size_t)(s * 8 + prow) * CQ + pblk * 8], &sK[0][s * 512]);
    async_copy16(&vb[(size_t)(s * 8 + prow) * TQ + 0 + pblk * 8], &sV[0][s * 512]);
  }

  float l_lane[4] = {0.f, 0.f, 0.f, 0.f};
  floatx4 oacc[4];
#pragma unroll
  for (int r = 0; r < 4; r++) oacc[r] = floatx4{0.f, 0.f, 0.f, 0.f};

  for (int jt = 0; jt < 16; jt++) {
    const int cur = jt & 1, nx = cur ^ 1;
    __syncthreads();
    if (jt < 15) {
      const int j0n = (jt + 1) * 64;
#pragma unroll
      for (int q = 0; q < 2; q++) {
        int s = w * 2 + q;
        async_copy16(&kb[(size_t)(j0n + s * 8 + prow) * CQ + pblk * 8],
                     &sK[nx][s * 512]);
        async_copy16(&vb[(size_t)(s * 8 + prow) * TQ + j0n + pblk * 8],
                     &sV[nx][s * 512]);
      }
    }
    const int j0 = jt * 64;

    floatx4 sc[4];
#pragma unroll
    for (int jg = 0; jg < 4; jg++) {
      const int r = (jg * 16 + col) * 64;
      short8 kf0 = *(const short8*)&sK[cur][r + eblk0];
      short8 kf1 = *(const short8*)&sK[cur][r + eblk1];
      floatx4 z = {0.f, 0.f, 0.f, 0.f};
      z = MFMA16(qf0, kf0, z);
      sc[jg] = MFMA16(qf1, kf1, z);
    }

    const bool inband = (j0 <= i0 + 19) && (j0 + 63 >= i0 - 4);

    float p[4][4];
#pragma unroll
    for (int reg = 0; reg < 4; reg++) {
      const int ig = i0 + g * 4 + reg;
#pragma unroll
      for (int jg = 0; jg < 4; jg++) {
        float s = sc[jg][reg];
        if (inband) {
          int dlt = j0 + jg * 16 + col - ig + 4;
          if (dlt >= 0 && dlt < 9) s += rkdl[w][g * 4 + reg][dlt];
        }
        float pv = (smask[j0 + jg * 16 + col] == 0.f) ? 0.f : __expf(s);
        p[reg][jg] = pv;
        l_lane[reg] += pv;
      }
    }

    if (inband) {
#pragma unroll
      for (int reg = 0; reg < 4; reg++) {
        const int row = g * 4 + reg;
#pragma unroll
        for (int jg = 0; jg < 4; jg++) {
          int dlt = j0 + jg * 16 + col - (i0 + row) + 4;
          if (dlt >= 0 && dlt < 9) pband[w][row][dlt] = p[reg][jg];
        }
      }
    }

#pragma unroll
    for (int reg = 0; reg < 4; reg++)
#pragma unroll
      for (int jg = 0; jg < 4; jg++)
        pbuf[w][g * 4 + reg][jg * 16 + col] = f2bf(p[reg][jg]);
    __builtin_amdgcn_wave_barrier();
    short8 pf0 = *(const short8*)&pbuf[w][col][g * 8];
    short8 pf1 = *(const short8*)&pbuf[w][col][32 + g * 8];

#pragma unroll
    for (int dg = 0; dg < 4; dg++) {
      const int r = (dg * 16 + col) * 64;
      short8 vf0 = *(const short8*)&sV[cur][r + eblk0];
      short8 vf1 = *(const short8*)&sV[cur][r + eblk1];
      oacc[dg] = MFMA16(pf0, vf0, oacc[dg]);
      oacc[dg] = MFMA16(pf1, vf1, oacc[dg]);
    }
    __builtin_amdgcn_wave_barrier();
  }

  float inv_l[4];
#pragma unroll
  for (int reg = 0; reg < 4; reg++) {
    float l = l_lane[reg];
#pragma unroll
    for (int off = 1; off < 16; off <<= 1) l += __shfl_xor(l, off, 64);
    inv_l[reg] = 1.f / l;
  }

#pragma unroll
  for (int dg = 0; dg < 4; dg++) {
    float rvc[4] = {0.f, 0.f, 0.f, 0.f};
#pragma unroll
    for (int dlt = 0; dlt < 9; dlt++) {
      float rvv = rv[dlt * 64 + dg * 16 + col];
#pragma unroll
      for (int reg = 0; reg < 4; reg++)
        rvc[reg] += pband[w][g * 4 + reg][dlt] * rvv;
    }
#pragma unroll
    for (int reg = 0; reg < 4; reg++) {
      float val = (oacc[dg][reg] + rvc[reg]) * inv_l[reg];
      ob[(size_t)(i0 + g * 4 + reg) * CQ + dg * 16 + col] = f2bf(val);
    }
  }
}

// ---------------------------------------------------------------------------
// Residual + LayerNorm rows (C=512 contiguous). v = res + s*(a1+a2+addb[c]),
// s = mask if (mode&1). y = LN(v)*g+b; if (mode&2) y *= mask.
// ---------------------------------------------------------------------------
__global__ __launch_bounds__(256) void ln_rows(
    const float* __restrict__ res, const float* __restrict__ a1,
    const float* __restrict__ a2, const float* __restrict__ addb,
    const float* __restrict__ g, const float* __restrict__ bb,
    const float* __restrict__ mask, float* __restrict__ outf,
    unsigned short* __restrict__ outb, int mode)
{
  const int row = blockIdx.x * 4 + (threadIdx.x >> 6);
  const int lane = threadIdx.x & 63;
  const size_t base = (size_t)row * CQ + lane * 8;
  const int c0 = lane * 8;

  float mv = mask[row];
  float sadd = (mode & 1) ? mv : 1.f;

  float v[8];
#pragma unroll
  for (int i = 0; i < 8; i += 4) {
    float4 r = *(const float4*)&res[base + i];
    float4 x1 = *(const float4*)&a1[base + i];
    float4 x2 = *(const float4*)&a2[base + i];
    float4 bv = *(const float4*)&addb[c0 + i];
    v[i + 0] = r.x + sadd * (x1.x + x2.x + bv.x);
    v[i + 1] = r.y + sadd * (x1.y + x2.y + bv.y);
    v[i + 2] = r.z + sadd * (x1.z + x2.z + bv.z);
    v[i + 3] = r.w + sadd * (x1.w + x2.w + bv.w);
  }
  float sum = 0.f, ssq = 0.f;
#pragma unroll
  for (int i = 0; i < 8; i++) { sum += v[i]; ssq += v[i] * v[i]; }
#pragma unroll
  for (int off = 1; off < 64; off <<= 1) {
    sum += __shfl_xor(sum, off, 64);
    ssq += __shfl_xor(ssq, off, 64);
  }
  float mean = sum * (1.f / CQ);
  float var = ssq * (1.f / CQ) - mean * mean;
  float rstd = rsqrtf(var + 1e-6f);
  float pm = (mode & 2) ? mv : 1.f;

  float y[8];
#pragma unroll
  for (int i = 0; i < 8; i++)
    y[i] = ((v[i] - mean) * rstd * g[c0 + i] + bb[c0 + i]) * pm;
  float4 o0 = {y[0], y[1], y[2], y[3]}, o1 = {y[4], y[5], y[6], y[7]};
  *(float4*)&outf[base] = o0;
  *(float4*)&outf[base + 4] = o1;
  if (outb) {
    ushort4 u0 = {f2bf(y[0]), f2bf(y[1]), f2bf(y[2]), f2bf(y[3])};
    ushort4 u1 = {f2bf(y[4]), f2bf(y[5]), f2bf(y[6]), f2bf(y[7])};
    *(ushort4*)&outb[base] = u0;
    *(ushort4*)&outb[base + 4] = u1;
  }
}

// ---------------------------------------------------------------------------
// Transpose-in: x (B,C,T) fp32 -> xa fp32 (B,T,C) + xab bf16 (B,T,C)
// ---------------------------------------------------------------------------
__global__ __launch_bounds__(256) void tr_in(
    const float* __restrict__ x, float* __restrict__ xa,
    unsigned short* __restrict__ xab)
{
  __shared__ float s[32][33];
  const int b = blockIdx.z, t0 = blockIdx.x * 32, c0 = blockIdx.y * 32;
  const int tx = threadIdx.x, ty = threadIdx.y;
#pragma unroll
  for (int r = 0; r < 4; r++)
    s[ty + r * 8][tx] = x[((size_t)b * CQ + c0 + ty + r * 8) * TQ + t0 + tx];
  __syncthreads();
#pragma unroll
  for (int r = 0; r < 4; r++) {
    float v = s[tx][ty + r * 8];
    size_t idx = ((size_t)b * TQ + t0 + ty + r * 8) * CQ + c0 + tx;
    xa[idx] = v;
    xab[idx] = f2bf(v);
  }
}

// ---------------------------------------------------------------------------
// Transpose-out: y (B,T,C) fp32 -> out (B,C,T) fp32
// ---------------------------------------------------------------------------
__global__ __launch_bounds__(256) void tr_out(
    const float* __restrict__ y, float* __restrict__ out)
{
  __shared__ float s[32][33];
  const int b = blockIdx.z, t0 = blockIdx.x * 32, c0 = blockIdx.y * 32;
  const int tx = threadIdx.x, ty = threadIdx.y;
#pragma unroll
  for (int r = 0; r < 4; r++)
    s[ty + r * 8][tx] = y[((size_t)b * TQ + t0 + ty + r * 8) * CQ + c0 + tx];
  __syncthreads();
#pragma unroll
  for (int r = 0; r < 4; r++)
    out[((size_t)b * CQ + c0 + ty + r * 8) * TQ + t0 + tx] = s[tx][ty + r * 8];
}

// ---------------------------------------------------------------------------
// ALL-layer weight fp32 -> bf16, one launch. Per-layer block (3,145,728 el):
// [qkv 786432][ow 262144][w1 1048576][w2 1048576]
// ---------------------------------------------------------------------------
__global__ __launch_bounds__(256) void wconv_all(
    const float* __restrict__ qw, const float* __restrict__ kw,
    const float* __restrict__ vw, const float* __restrict__ ow,
    const float* __restrict__ w1, const float* __restrict__ w2,
    unsigned short* __restrict__ dst)
{
  const int PER_L4 = 786432;                   // float4 groups per layer
  int idx4 = blockIdx.x * 256 + threadIdx.x;   // 3,145,728 total
  int l = idx4 / PER_L4;
  int e = (idx4 - l * PER_L4) * 4;             // elem within layer block
  const float* src;
  size_t off;
  if (e < 786432) {
    int which = e >> 18;
    src = (which == 0) ? qw : (which == 1) ? kw : vw;
    off = (size_t)l * 262144 + (e & 262143);
  } else if (e < 1048576) {
    src = ow;  off = (size_t)l * 262144 + (e - 786432);
  } else if (e < 2097152) {
    src = w1;  off = (size_t)l * 1048576 + (e - 1048576);
  } else {
    src = w2;  off = (size_t)l * 1048576 + (e - 2097152);
  }
  float4 v = *(const float4*)&src[off];
  ushort4 u = {f2bf(v.x), f2bf(v.y), f2bf(v.z), f2bf(v.w)};
  *(ushort4*)&dst[(size_t)l * 3145728 + e] = u;
}

// ---------------------------------------------------------------------------
extern "C" void kernel_launch(void* const* d_in, const int* in_sizes, int n_in,
                              void* d_out, int out_size, void* d_ws, size_t ws_size,
                              hipStream_t stream) {
  const float* x    = (const float*)d_in[0];
  const float* mask = (const float*)d_in[1];
  const float* qw   = (const float*)d_in[2];
  const float* qbb  = (const float*)d_in[3];
  const float* kw   = (const float*)d_in[4];
  const float* kbb  = (const float*)d_in[5];
  const float* vw   = (const float*)d_in[6];
  const float* vbb  = (const float*)d_in[7];
  const float* ow   = (const float*)d_in[8];
  const float* obb  = (const float*)d_in[9];
  const float* rk   = (const float*)d_in[10];
  const float* rv   = (const float*)d_in[11];
  const float* g1   = (const float*)d_in[12];
  const float* be1  = (const float*)d_in[13];
  const float* w1   = (const float*)d_in[14];
  const float* b1   = (const float*)d_in[15];
  const float* w2   = (const float*)d_in[16];
  const float* b2   = (const float*)d_in[17];
  const float* g2   = (const float*)d_in[18];
  const float* be2  = (const float*)d_in[19];
  float* out = (float*)d_out;

  const size_t MB = 1 << 20;
  char* base = (char*)d_ws;
  unsigned short* wbufA = (unsigned short*)(base);            // 24 MB (all layers)
  float*          xa    = (float*)(base + 24 * MB);           // 8 MB fp32 (B,T,C)
  unsigned short* xab   = (unsigned short*)(base + 32 * MB);  // 4 MB bf16 (B,T,C)
  unsigned short* qtb   = (unsigned short*)(base + 36 * MB);  // 4 MB
  unsigned short* ktb   = (unsigned short*)(base + 40 * MB);  // 4 MB
  unsigned short* vtb   = (unsigned short*)(base + 44 * MB);  // 4 MB (B,C,T)
  unsigned short* obufb = (unsigned short*)(base + 48 * MB);  // 4 MB (B,T,C)
  float*          t1    = (float*)(base + 52 * MB);           // 8 MB fp32
  // t1b = t1 + MT*CQ (@60 MB, 8 MB) -- split-K partial 2
  unsigned short* hbuf  = qtb;   // FFN hidden bf16 (B,T,F): 16 MB over 36..52

  const long long sY = (long long)MT * CQ;
  float* t1b = t1 + sY;

  dim3 b256(256);
  dim3 gtr(TQ / 32, CQ / 32, BQ);
  dim3 gln(MT / 4);

  hipLaunchKernelGGL(tr_in, gtr, dim3(32, 8), 0, stream, x, xa, xab);
  hipLaunchKernelGGL(wconv_all, dim3(12288), b256, 0, stream,
      qw, kw, vw, ow, w1, w2, wbufA);

  for (int i = 0; i < LQ; i++) {
    const unsigned short* wl  = wbufA + (size_t)i * 3145728;
    const unsigned short* wo  = wl + 786432;
    const unsigned short* wf1 = wl + 1048576;
    const unsigned short* wf2 = wl + 2097152;
    // fused QKV: (4096 x 1536), V written transposed (B,C,T); 384 blocks
    hipLaunchKernelGGL(qkv_gemm, dim3(12, 32), b256, 0, stream,
        xab, wl, qtb, ktb, vtb, qbb + i * CQ, kbb + i * CQ, vbb + i * CQ);
    // attention: 64 Q rows/block, LDS-dbuf cooperative staging (512 blocks)
    hipLaunchKernelGGL(attn_kernel, dim3(TQ / 64, HQ, BQ), b256, 0, stream,
        qtb, ktb, vtb, mask, rk + (size_t)i * 576, rv + (size_t)i * 576, obufb);
    // o-proj split-K=2, 128x64 tiles -> 512 blocks, raw partials t1/t1b
    hipLaunchKernelGGL(mfma_gemm64, dim3(8, 32, 2), b256, 0, stream,
        obufb, wo, t1, MT, CQ, CQ / 2, CQ, CQ, (long long)(CQ / 2), sY);
    hipLaunchKernelGGL(ln_rows, gln, b256, 0, stream,
        xa, t1, t1b, obb + i * CQ, g1 + i * CQ, be1 + i * CQ, mask,
        xa, xab, 0);
    // FFN1 (512 blocks): premask+relu+postmask, bf16 out
    hipLaunchKernelGGL(mfma_gemm, dim3(16, 32, 1), b256, 0, stream,
        xab, wf1, (void*)hbuf, b1 + i * FQ, mask,
        MT, FQ, CQ, CQ, CQ, 0LL, 0LL, 1.f, 1 | 2 | 4 | 16);
    // FFN2 split-K=2, 128x64 tiles -> 512 blocks, raw partials
    hipLaunchKernelGGL(mfma_gemm64, dim3(8, 32, 2), b256, 0, stream,
        hbuf, wf2, t1, MT, CQ, FQ / 2, FQ, FQ, (long long)(FQ / 2), sY);
    hipLaunchKernelGGL(ln_rows, gln, b256, 0, stream,
        xa, t1, t1b, b2 + i * CQ, g2 + i * CQ, be2 + i * CQ, mask,
        xa, xab, 3);
  }
  hipLaunchKernelGGL(tr_out, gtr, dim3(32, 8), 0, stream, xa, out);
}